// Round 11
// baseline (383.890 us; speedup 1.0000x reference)
//
#include <hip/hip_runtime.h>
#include <math.h>

#define NB 4
#define CIN 64
#define CO 64
#define CM 32
#define H0 48
#define W0 48
#define HH 96
#define WW 96
#define LTOK (HH*WW)     // 9216 tokens per image
#define NH 4
#define NBUCK 64
#define CHUNK 144
#define NCHUNK 64        // LTOK / CHUNK
#define TOT (NH*LTOK)    // 36864
#define SB 512
#define NSB (TOT/SB)     // 72

typedef __attribute__((ext_vector_type(8))) short short8;
typedef __attribute__((ext_vector_type(4))) short short4v;
typedef __attribute__((ext_vector_type(4))) float f32x4;

__device__ __forceinline__ short f2bf(float f) {          // RNE
  union { float f; unsigned u; } v; v.f = f;
  unsigned r = v.u + 0x7fffu + ((v.u >> 16) & 1u);
  return (short)(r >> 16);
}
__device__ __forceinline__ short f2bf_fast(float f) {     // round-half-up (1 add)
  union { float f; unsigned u; } v; v.f = f;
  return (short)((v.u + 0x8000u) >> 16);
}
__device__ __forceinline__ float bf2f(short h) {
  union { float f; unsigned u; } v; v.u = ((unsigned)(unsigned short)h) << 16;
  return v.f;
}
__device__ __forceinline__ short8 ld_b64x2(const short* p) {  // 8B-aligned pair load
  short4v a = *(const short4v*)p;
  short4v b = *(const short4v*)(p+4);
  short8 r; r[0]=a[0];r[1]=a[1];r[2]=a[2];r[3]=a[3];r[4]=b[0];r[5]=b[1];r[6]=b[2];r[7]=b[3];
  return r;
}

// ---------------- bicubic upsample (jax.image.resize, cubic a=-0.5, half-pixel) ----------------
__device__ __forceinline__ void cubic_taps(int o, int insz, int* p, float* w) {
  int j = o >> 1;
  const float B0=-0.0234375f, B1=0.2265625f, B2=0.8671875f, B3=-0.0703125f;
  if ((o & 1) == 0) { p[0]=j-2;p[1]=j-1;p[2]=j;  p[3]=j+1; w[0]=B0;w[1]=B1;w[2]=B2;w[3]=B3; }
  else              { p[0]=j-1;p[1]=j;  p[2]=j+1;p[3]=j+2; w[0]=B3;w[1]=B2;w[2]=B1;w[3]=B0; }
  float s = 0.f;
  #pragma unroll
  for (int a=0;a<4;a++){ if (p[a] < 0 || p[a] >= insz) p[a] = -1; else s += w[a]; }
  float inv = 1.f / s;
  #pragma unroll
  for (int a=0;a<4;a++) w[a] *= inv;
}

__global__ void k_upsample(const float* __restrict__ x, float* __restrict__ up) {
  int i = blockIdx.x*blockDim.x + threadIdx.x;
  if (i >= NB*CIN*HH*WW) return;
  int ox = i % WW; int t = i / WW;
  int oy = t % HH; t /= HH;
  int c = t % CIN; int n = t / CIN;
  int px[4]; float wx[4]; cubic_taps(ox, W0, px, wx);
  int py[4]; float wy[4]; cubic_taps(oy, H0, py, wy);
  const float* src = x + ((size_t)(n*CIN + c))*H0*W0;
  float acc = 0.f;
  #pragma unroll
  for (int a=0;a<4;a++) {
    if (py[a] < 0) continue;
    const float* r = src + py[a]*W0;
    float ra = 0.f;
    #pragma unroll
    for (int b=0;b<4;b++) if (px[b] >= 0) ra = fmaf(wx[b], r[px[b]], ra);
    acc = fmaf(wy[a], ra, acc);
  }
  up[i] = acc;
}

// ---------------- weight prep (all three convs in ONE launch) + hist zeroing ----------------
__global__ void k_wprep3(const float* __restrict__ w1, const float* __restrict__ w2,
                         const float* __restrict__ wm, short* __restrict__ base,
                         int* __restrict__ hist) {
  int i = blockIdx.x*blockDim.x + threadIdx.x;
  if (i < 73728) hist[i] = 0;                 // k_cmhash accumulates with atomics
  if (i >= 92160) return;
  const float* src; short *dH, *dL; int couts, j;
  if (i < 36864)      { src = w1; couts = 64; j = i;          dH = base;          dL = base + 36864; }
  else if (i < 73728) { src = w2; couts = 64; j = i - 36864;  dH = base + 73728;  dL = base + 110592; }
  else                { src = wm; couts = 32; j = i - 73728;  dH = base + 147456; dL = base + 165888; }
  int ci = j & 63; int t = j >> 6; int co = t % couts; int s = t / couts;
  float v = src[((size_t)(co*64 + ci))*9 + s];
  short hi = f2bf(v);
  dH[j] = hi;
  dL[j] = f2bf(v - bf2f(hi));
}

// ---------------- 3x3 conv as implicit GEMM, K=64 stages, 32-co blocks ----------------------
#define XP 68   // X LDS pitch in shorts (136B: 8B-aligned b64 frags)
#define WP 72   // W LDS pitch in shorts (144B: 16B-aligned b128 frags)
template<int TOKS, bool TMAJ, bool RELU>
__global__ __launch_bounds__(256) void k_conv3m(const float* __restrict__ in,
                          const short* __restrict__ wH, const short* __restrict__ wL,
                          const float* __restrict__ bias, float* __restrict__ out,
                          int couts_tot, int cosplit) {
  int blk = blockIdx.x;              // NB * (LTOK/TOKS) * cosplit
  int ch = blk % cosplit;
  int tb = (blk / cosplit) % (LTOK/TOKS);
  int n  = blk / (cosplit * (LTOK/TOKS));
  int t0 = tb * TOKS;
  int co0 = ch * 32;
  int tid = threadIdx.x;
  int wv = tid >> 6, lane = tid & 63, quad = lane >> 4, l16 = lane & 15;
  __shared__ __align__(16) short XB[TOKS*XP];
  __shared__ __align__(16) short WHs[32*WP];
  __shared__ __align__(16) short WLs[32*WP];
  __shared__ float biasl[32];
  if (tid < 32) biasl[tid] = bias[co0 + tid];
  constexpr int TSH = (TOKS == 128) ? 7 : 6;
  f32x4 acc[2][2];
  #pragma unroll
  for (int a=0;a<2;a++)
    #pragma unroll
    for (int b=0;b<2;b++) acc[a][b] = (f32x4){0.f,0.f,0.f,0.f};

  const float* inb = in + (size_t)n*CIN*LTOK;
  for (int s = 0; s < 9; s++) {
    int dy = s/3 - 1, dx = s%3 - 1;
    __syncthreads();
    #pragma unroll
    for (int it = 0; it < (TOKS*32)/256; it++) {
      int idx = tid + 256*it;
      int tok = idx & (TOKS-1), c = idx >> TSH;
      int t = t0 + tok;
      int y = t / WW, x = t - y*WW;
      int ys = y + dy, xs = x + dx;
      float v0 = 0.f, v1 = 0.f;
      if ((unsigned)ys < HH && (unsigned)xs < WW) {
        const float* p = inb + ((size_t)(2*c))*LTOK + ys*WW + xs;
        v0 = p[0]; v1 = p[LTOK];
      }
      unsigned pk = (unsigned)(unsigned short)f2bf(v0) | (((unsigned)(unsigned short)f2bf(v1)) << 16);
      ((unsigned*)XB)[tok*(XP/2) + c] = pk;
    }
    #pragma unroll
    for (int it = 0; it < 8; it++) {
      int idx = tid + 256*it;
      int plane = idx >> 10, rem = idx & 1023;
      int co = rem >> 5, d = rem & 31;
      const unsigned* srcw = (const unsigned*)(plane ? wL : wH);
      unsigned v = srcw[(size_t)(s*couts_tot + co0 + co)*32 + d];
      unsigned* dst = (unsigned*)(plane ? WLs : WHs);
      dst[co*(WP/2) + d] = v;
    }
    __syncthreads();
    #pragma unroll
    for (int kf = 0; kf < 2; kf++) {
      if (!TMAJ) {
        short8 xf[2];
        #pragma unroll
        for (int nt=0;nt<2;nt++)
          xf[nt] = ld_b64x2(&XB[(wv*32 + nt*16 + l16)*XP + kf*32 + quad*8]);
        #pragma unroll
        for (int mt=0;mt<2;mt++) {
          short8 wh = *(const short8*)&WHs[(mt*16 + l16)*WP + kf*32 + quad*8];
          short8 wl = *(const short8*)&WLs[(mt*16 + l16)*WP + kf*32 + quad*8];
          #pragma unroll
          for (int nt=0;nt<2;nt++) {
            acc[mt][nt] = __builtin_amdgcn_mfma_f32_16x16x32_bf16(wh, xf[nt], acc[mt][nt], 0, 0, 0);
            acc[mt][nt] = __builtin_amdgcn_mfma_f32_16x16x32_bf16(wl, xf[nt], acc[mt][nt], 0, 0, 0);
          }
        }
      } else {
        short8 xf = ld_b64x2(&XB[(wv*16 + l16)*XP + kf*32 + quad*8]);
        #pragma unroll
        for (int nt=0;nt<2;nt++) {
          short8 wh = *(const short8*)&WHs[(nt*16 + l16)*WP + kf*32 + quad*8];
          short8 wl = *(const short8*)&WLs[(nt*16 + l16)*WP + kf*32 + quad*8];
          acc[0][nt] = __builtin_amdgcn_mfma_f32_16x16x32_bf16(xf, wh, acc[0][nt], 0, 0, 0);
          acc[0][nt] = __builtin_amdgcn_mfma_f32_16x16x32_bf16(xf, wl, acc[0][nt], 0, 0, 0);
        }
      }
    }
  }
  if (!TMAJ) {   // D[m=co][n=tok] -> NCHW
    #pragma unroll
    for (int mt=0;mt<2;mt++) {
      #pragma unroll
      for (int nt=0;nt<2;nt++) {
        int tokl = wv*32 + nt*16 + l16;
        #pragma unroll
        for (int reg=0;reg<4;reg++) {
          int col = mt*16 + quad*4 + reg;
          float v = acc[mt][nt][reg] + biasl[col];
          if (RELU) v = fmaxf(v, 0.f);
          out[((size_t)(n*couts_tot + co0 + col))*LTOK + t0 + tokl] = v;
        }
      }
    }
  } else {       // D[m=tok][n=co] -> token-major
    #pragma unroll
    for (int nt=0;nt<2;nt++) {
      int co = nt*16 + l16;
      #pragma unroll
      for (int reg=0;reg<4;reg++) {
        int t = t0 + wv*16 + quad*4 + reg;
        float v = acc[0][nt][reg] + biasl[co];
        if (RELU) v = fmaxf(v, 0.f);
        out[((size_t)n*LTOK + t)*couts_tot + co] = v;
      }
    }
  }
}

// ---------------- FUSED conv_match (MFMA) + LSH hash + token prep ---------------------------
// conv tile (64 tok x 32 ch, fp32) stays in LDS; hash phase: 256 thr = 64 tok x 4 h.
// xep is never materialized. hist via global atomics (zeroed in k_wprep3).
__global__ __launch_bounds__(256) void k_cmhash(const float* __restrict__ in,
                          const short* __restrict__ wH, const short* __restrict__ wL,
                          const float* __restrict__ bias, const float* __restrict__ rot,
                          int* __restrict__ codes, int* __restrict__ hist,
                          short* __restrict__ xqb, short* __restrict__ xkb,
                          float* __restrict__ qnb) {
  int blk = blockIdx.x;              // NB*144
  int n  = blk / 144;
  int t0 = (blk % 144) * 64;
  int tid = threadIdx.x;
  int wv = tid >> 6, lane = tid & 63, quad = lane >> 4, l16 = lane & 15;
  __shared__ __align__(16) short XB[64*XP];
  __shared__ __align__(16) short WHs[32*WP];
  __shared__ __align__(16) short WLs[32*WP];
  __shared__ float biasl[32];
  __shared__ float xm[64][33];       // conv output tile fp32 (pad -> 2-way free)
  __shared__ float rl[NH][32][32];   // [h][f][i]
  if (tid < 32) biasl[tid] = bias[tid];
  for (int e = tid; e < NH*32*32; e += 256) {
    int i = e & 31, f = (e >> 5) & 31, h = e >> 10;
    rl[h][f][i] = rot[(f*NH + h)*32 + i];
  }
  f32x4 acc[2];
  acc[0] = (f32x4){0.f,0.f,0.f,0.f}; acc[1] = (f32x4){0.f,0.f,0.f,0.f};

  const float* inb = in + (size_t)n*CIN*LTOK;
  for (int s = 0; s < 9; s++) {
    int dy = s/3 - 1, dx = s%3 - 1;
    __syncthreads();
    #pragma unroll
    for (int it = 0; it < 8; it++) {
      int idx = tid + 256*it;
      int tok = idx & 63, c = idx >> 6;
      int t = t0 + tok;
      int y = t / WW, x = t - y*WW;
      int ys = y + dy, xs = x + dx;
      float v0 = 0.f, v1 = 0.f;
      if ((unsigned)ys < HH && (unsigned)xs < WW) {
        const float* p = inb + ((size_t)(2*c))*LTOK + ys*WW + xs;
        v0 = p[0]; v1 = p[LTOK];
      }
      unsigned pk = (unsigned)(unsigned short)f2bf(v0) | (((unsigned)(unsigned short)f2bf(v1)) << 16);
      ((unsigned*)XB)[tok*(XP/2) + c] = pk;
    }
    #pragma unroll
    for (int it = 0; it < 8; it++) {
      int idx = tid + 256*it;
      int plane = idx >> 10, rem = idx & 1023;
      int co = rem >> 5, d = rem & 31;
      const unsigned* srcw = (const unsigned*)(plane ? wL : wH);
      unsigned v = srcw[(size_t)(s*32 + co)*32 + d];
      unsigned* dst = (unsigned*)(plane ? WLs : WHs);
      dst[co*(WP/2) + d] = v;
    }
    __syncthreads();
    #pragma unroll
    for (int kf = 0; kf < 2; kf++) {
      short8 xf = ld_b64x2(&XB[(wv*16 + l16)*XP + kf*32 + quad*8]);
      #pragma unroll
      for (int nt=0;nt<2;nt++) {
        short8 wh = *(const short8*)&WHs[(nt*16 + l16)*WP + kf*32 + quad*8];
        short8 wl = *(const short8*)&WLs[(nt*16 + l16)*WP + kf*32 + quad*8];
        acc[nt] = __builtin_amdgcn_mfma_f32_16x16x32_bf16(xf, wh, acc[nt], 0, 0, 0);
        acc[nt] = __builtin_amdgcn_mfma_f32_16x16x32_bf16(xf, wl, acc[nt], 0, 0, 0);
      }
    }
  }
  // epilogue: conv tile -> LDS (same fp32 values the old kernel wrote to xep)
  #pragma unroll
  for (int nt=0;nt<2;nt++) {
    int co = nt*16 + l16;
    #pragma unroll
    for (int reg=0;reg<4;reg++) {
      int tl = wv*16 + quad*4 + reg;
      xm[tl][co] = acc[nt][reg] + biasl[co];
    }
  }
  __syncthreads();
  // ---- hash phase: thread = (tok, h) ----
  int tok = tid & 63, h = tid >> 6;
  int t = t0 + tok;
  float q[32];
  #pragma unroll
  for (int f = 0; f < 32; f++) q[f] = xm[tok][f];
  if (h == 0) {   // token prep once per token (same f-order math as before)
    float ssq = 0.f;
    #pragma unroll
    for (int f = 0; f < 32; f++) ssq = fmaf(q[f], q[f], ssq);
    float nrm = sqrtf(ssq);
    float rn = 1.f / fmaxf(nrm, 5e-5f);
    qnb[(size_t)n*LTOK + t] = nrm;
    #pragma unroll
    for (int r = 0; r < 4; r++) {
      short8 q8, k8;
      #pragma unroll
      for (int jj = 0; jj < 8; jj++) { q8[jj] = f2bf(q[8*r+jj]); k8[jj] = f2bf(q[8*r+jj]*rn); }
      *(short8*)&xqb[((size_t)n*LTOK + t)*CM + 8*r] = q8;
      *(short8*)&xkb[((size_t)n*LTOK + t)*CM + 8*r] = k8;
    }
  }
  float bp = -INFINITY, bn = -INFINITY; int ip = 0, inn = 0;
  for (int i = 0; i < 32; i++) {
    float a = 0.f;
    #pragma unroll
    for (int f = 0; f < 32; f++) a = fmaf(q[f], rl[h][f][i], a);
    if (a  > bp) { bp = a;  ip  = i; }
    if (-a > bn) { bn = -a; inn = i; }
  }
  int code = ((bp >= bn) ? ip : (32 + inn)) + h * NBUCK;
  codes[n*TOT + h*LTOK + t] = code;
  int bb = (h*LTOK + t) >> 9;    // 64-aligned tile never straddles a 512 boundary
  atomicAdd(&hist[((size_t)(n*256 + code))*NSB + bb], 1);
}

// ---------------- 1x1 conv as LDS-tiled GEMM -> bf16 token-major V [n][t][64] ----------------
__global__ __launch_bounds__(256) void k_conv1x1(const float* __restrict__ in, const float* __restrict__ w,
                          const float* __restrict__ bias, short* __restrict__ out) {
  int blk = blockIdx.x;           // NB * 72
  int n  = blk / (LTOK/128);
  int t0 = (blk % (LTOK/128)) * 128;
  int tid = threadIdx.x;
  __shared__ float Wl[64*64];     // [ci][co]
  __shared__ float Xl[64][128];
  for (int e=tid; e<4096; e+=256) {
    int ci=e>>6, co=e&63;
    Wl[e] = w[co*CIN + ci];
  }
  for (int e=tid; e<64*128; e+=256) {
    int ci=e>>7, t=e&127;
    Xl[ci][t] = in[(size_t)n*CIN*LTOK + (size_t)ci*LTOK + t0 + t];
  }
  __syncthreads();
  int co = tid & 63, tg = tid >> 6;
  float acc[32];
  float bv = bias[co];
  #pragma unroll
  for (int i=0;i<32;i++) acc[i]=bv;
  for (int ci=0;ci<64;ci++){
    float wv = Wl[ci*64+co];
    const float4* xr = (const float4*)&Xl[ci][tg*32];
    #pragma unroll
    for (int r=0;r<8;r++){
      float4 xv = xr[r];
      acc[4*r+0]=fmaf(wv,xv.x,acc[4*r+0]);
      acc[4*r+1]=fmaf(wv,xv.y,acc[4*r+1]);
      acc[4*r+2]=fmaf(wv,xv.z,acc[4*r+2]);
      acc[4*r+3]=fmaf(wv,xv.w,acc[4*r+3]);
    }
  }
  short* ob = out + ((size_t)n*LTOK + t0 + tg*32)*CO + co;
  #pragma unroll
  for (int i=0;i<32;i++) ob[(size_t)i*CO] = f2bf(acc[i]);
}

// ---------------- stable counting sort (transposed hist: contiguous per-thread runs) --------
__global__ void k_offsets(const int* __restrict__ hist, int* __restrict__ bstart) {
  int n = blockIdx.x; int c = threadIdx.x;
  const int* hrow = hist + (size_t)(n*256 + c)*NSB;
  int tot = 0;
  for (int b = 0; b < NSB; b++) tot += hrow[b];
  __shared__ int sc[256];
  sc[c] = tot;
  __syncthreads();
  for (int d = 1; d < 256; d <<= 1) {
    int u = (c >= d) ? sc[c-d] : 0;
    __syncthreads();
    sc[c] += u;
    __syncthreads();
  }
  int run = sc[c] - tot;
  int* brow = bstart + (size_t)(n*256 + c)*NSB;
  for (int b = 0; b < NSB; b++) {
    brow[b] = run;
    run += hrow[b];
  }
}

// ballot-based stable rank: rank = #earlier-threads-in-block with same code.
__global__ void k_scatter(const int* __restrict__ codes, const int* __restrict__ bstart,
                          int* __restrict__ sidx) {
  int b = blockIdx.x; int n = b / NSB; int bb = b % NSB;
  int tid = threadIdx.x;
  int j = bb*SB + tid;
  int code = codes[n*TOT + j];
  int wave = tid >> 6, lane = tid & 63;
  __shared__ int wcnt[8][256];
  for (int e = tid; e < 8*256; e += SB) ((int*)wcnt)[e] = 0;
  __syncthreads();
  unsigned long long mask = ~0ULL;
  #pragma unroll
  for (int bit = 0; bit < 8; bit++) {
    unsigned long long bal = __ballot((code >> bit) & 1);
    mask &= ((code >> bit) & 1) ? bal : ~bal;
  }
  unsigned long long lt = (lane == 63) ? 0x7FFFFFFFFFFFFFFFULL : ((1ULL << lane) - 1ULL);
  int rank_w = __popcll(mask & lt);
  if (rank_w == 0) wcnt[wave][code] = __popcll(mask);
  __syncthreads();
  int rank = rank_w;
  for (int w2 = 0; w2 < 8; w2++) {
    if (w2 >= wave) break;
    rank += wcnt[w2][code];
  }
  int pos = bstart[((size_t)(n*256 + code))*NSB + bb] + rank;
  sidx[n*TOT + pos] = j;
}

// ---------------- MFMA bf16 flash attention: 2 chunks/block, batched S -> batched PV --------
// XCD-aware block swizzle: blk&7 ~ XCD slot (round-robin dispatch heuristic); pin each image
// to 2 XCD slots so its ~2.4MB K/Q/V working set stays in one XCD's 4MB L2.
#define PQP 168   // P / V^T pitch in shorts (160 key cols + 8 pad; 16B aligned)
__global__ __launch_bounds__(192,1) void k_attn(const short* __restrict__ xqb,
                       const short* __restrict__ xkb, const float* __restrict__ qnb,
                       const short* __restrict__ yvb, const int* __restrict__ sidx,
                       short* __restrict__ ret, float* __restrict__ bsc) {
  int raw = blockIdx.x;               // 512 = NB*NH*NCHUNK/2
  int xcd = raw & 7;
  int n = xcd >> 1;
  int idx2 = ((raw >> 3) << 1) | (xcd & 1);   // 0..127
  int h = idx2 >> 5;
  int cpair = idx2 & 31;
  const int base = n*TOT + h*LTOK;
  __shared__ __align__(16) short Pq[144*PQP];   // P (bf16), cols 144..159 zero pad
  __shared__ __align__(16) short VbT[64*PQP];   // V^T bf16 [ch][key], cols 144..159 zero pad
  __shared__ int sj[3*CHUNK];
  int tid = threadIdx.x;
  int w = tid >> 6, lane = tid & 63, quad = lane >> 4, l16 = lane & 15;
  const short* xq = xqb + (size_t)n*LTOK*CM;
  const short* xk = xkb + (size_t)n*LTOK*CM;
  const short* yv = yvb + (size_t)n*LTOK*CO;
  const float* qn = qnb + (size_t)n*LTOK;

  // one-time zero of the PV over-read pad cols 144..159 in BOTH P and V^T.
  for (int e = tid; e < 144*8; e += 192) {
    int r = e >> 3, d = e & 7;
    ((unsigned*)Pq)[r*(PQP/2) + 72 + d] = 0u;
  }
  for (int e = tid; e < 64*8; e += 192) {
    int r = e >> 3, d = e & 7;
    ((unsigned*)VbT)[r*(PQP/2) + 72 + d] = 0u;
  }

  for (int ch2 = 0; ch2 < 2; ch2++) {
    int kch = cpair*2 + ch2;
    int kprev = (kch + NCHUNK - 1) & (NCHUNK-1), knext = (kch + 1) & (NCHUNK-1);
    __syncthreads();
    for (int e = tid; e < 3*CHUNK; e += 192) {
      int tt = e / CHUNK, r = e - tt*CHUNK;
      int kk = (tt==0) ? kch : ((tt==1) ? kprev : knext);
      sj[e] = sidx[base + kk*CHUNK + r];
    }
    __syncthreads();
    short8 qfrag[3]; float m_ln[3][4];
    #pragma unroll
    for (int mt=0;mt<3;mt++) {
      int tok = sj[48*w + 16*mt + l16] % LTOK;
      qfrag[mt] = *(const short8*)(xq + (size_t)tok*CM + quad*8);
      #pragma unroll
      for (int r=0;r<4;r++)
        m_ln[mt][r] = qn[sj[48*w + 16*mt + 4*quad + r] % LTOK];
    }
    f32x4 acc[3][4];
    #pragma unroll
    for (int mt=0;mt<3;mt++)
      #pragma unroll
      for (int nt=0;nt<4;nt++) acc[mt][nt] = (f32x4){0.f,0.f,0.f,0.f};
    float sspart[12];
    #pragma unroll
    for (int i=0;i<12;i++) sspart[i]=0.f;

    for (int tt = 0; tt < 3; tt++) {
      __syncthreads();
      #pragma unroll
      for (int it = 0; it < 6; it++) {
        int idx = tid + 192*it;
        int g = idx / CHUNK, key = idx - g*CHUNK;
        int tok = sj[tt*CHUNK + key] % LTOK;
        short8 v = *(const short8*)(yv + (size_t)tok*CO + 8*g);
        #pragma unroll
        for (int i=0;i<8;i++) VbT[(8*g+i)*PQP + key] = v[i];
      }
      __syncthreads();
      int ktok[9];
      #pragma unroll
      for (int nt=0;nt<9;nt++) ktok[nt] = sj[tt*CHUNK + 16*nt + l16] % LTOK;
      #pragma unroll
      for (int nt = 0; nt < 9; nt++) {
        short8 bfr = *(const short8*)(xk + (size_t)ktok[nt]*CM + quad*8);
        f32x4 c[3];
        #pragma unroll
        for (int mt=0;mt<3;mt++)
          c[mt] = __builtin_amdgcn_mfma_f32_16x16x32_bf16(qfrag[mt], bfr, (f32x4){0.f,0.f,0.f,0.f}, 0, 0, 0);
        #pragma unroll
        for (int mt=0;mt<3;mt++) {
          #pragma unroll
          for (int reg=0;reg<4;reg++) {
            float p = __expf(c[mt][reg] - m_ln[mt][reg]);
            sspart[mt*4+reg] += p;
            Pq[(48*w + 16*mt + 4*quad + reg)*PQP + 16*nt + l16] = f2bf_fast(p);
          }
        }
      }
      #pragma unroll
      for (int kf = 0; kf < 5; kf++) {
        short8 afr[3];
        #pragma unroll
        for (int mt=0;mt<3;mt++)
          afr[mt] = *(const short8*)&Pq[(48*w + 16*mt + l16)*PQP + kf*32 + quad*8];
        #pragma unroll
        for (int nt2=0;nt2<4;nt2++) {
          short8 vfr = *(const short8*)&VbT[(16*nt2 + l16)*PQP + kf*32 + quad*8];
          #pragma unroll
          for (int mt=0;mt<3;mt++)
            acc[mt][nt2] = __builtin_amdgcn_mfma_f32_16x16x32_bf16(afr[mt], vfr, acc[mt][nt2], 0, 0, 0);
        }
      }
    }
    #pragma unroll
    for (int i=0;i<12;i++) {
      float v = sspart[i];
      v += __shfl_xor(v, 1); v += __shfl_xor(v, 2);
      v += __shfl_xor(v, 4); v += __shfl_xor(v, 8);
      sspart[i] = v;
    }
    #pragma unroll
    for (int mt=0;mt<3;mt++) {
      #pragma unroll
      for (int reg=0;reg<4;reg++) {
        int row = 48*w + 16*mt + 4*quad + reg;
        int mtok = sj[row];
        float ssum = sspart[mt*4+reg];
        float inv = 1.f / ssum;
        short* rp = ret + ((size_t)n*TOT + mtok)*CO;
        #pragma unroll
        for (int nt2=0;nt2<4;nt2++) rp[16*nt2 + l16] = f2bf(acc[mt][nt2][reg] * inv);
        if (l16 == 0) bsc[(size_t)n*TOT + mtok] = m_ln[mt][reg] + logf(ssum);
      }
    }
  }
}

// ---------------- combine 4 hash rounds (softmax over bscore) + residual, NCHW out ----------
__global__ void k_combine(const short* __restrict__ ret, const float* __restrict__ bsc,
                          const float* __restrict__ c2, float* __restrict__ out) {
  int blk = blockIdx.x;                 // NB * (LTOK/16)
  int n  = blk / (LTOK/16);
  int t0 = (blk % (LTOK/16)) * 16;
  __shared__ float rl[NH][16][CO+1];
  __shared__ float pw[NH][16];
  int tid = threadIdx.x;
  for (int h = 0; h < NH; h++)
    for (int e = tid; e < 16*CO; e += 256) {
      int tl = e >> 6, f = e & 63;
      rl[h][tl][f] = bf2f(ret[((size_t)n*TOT + h*LTOK + t0 + tl)*CO + f]);
    }
  if (tid < 16) {
    float b0[NH]; float mm = -INFINITY;
    #pragma unroll
    for (int h = 0; h < NH; h++) { b0[h] = bsc[(size_t)n*TOT + h*LTOK + t0 + tid]; mm = fmaxf(mm, b0[h]); }
    float s = 0.f;
    #pragma unroll
    for (int h = 0; h < NH; h++) { b0[h] = __expf(b0[h] - mm); s += b0[h]; }
    float inv = 1.f / s;
    #pragma unroll
    for (int h = 0; h < NH; h++) pw[h][tid] = b0[h] * inv;
  }
  __syncthreads();
  int tl = tid & 15;
  int cog = tid >> 4;
  #pragma unroll
  for (int cc = 0; cc < 4; cc++) {
    int co = cog + 16*cc;
    size_t oi = ((size_t)(n*CO + co))*LTOK + t0 + tl;
    float a = c2[oi];
    #pragma unroll
    for (int h = 0; h < NH; h++) a = fmaf(pw[h][tl], rl[h][tl][co], a);
    out[oi] = a;
  }
}

extern "C" void kernel_launch(void* const* d_in, const int* in_sizes, int n_in,
                              void* d_out, int out_size, void* d_ws, size_t ws_size,
                              hipStream_t stream) {
  const float* x   = (const float*)d_in[0];
  const float* w1  = (const float*)d_in[1];
  const float* b1  = (const float*)d_in[2];
  const float* w2  = (const float*)d_in[3];
  const float* b2  = (const float*)d_in[4];
  const float* wm  = (const float*)d_in[5];
  const float* bm  = (const float*)d_in[6];
  const float* wa  = (const float*)d_in[7];
  const float* ba  = (const float*)d_in[8];
  const float* rot = (const float*)d_in[9];
  float* out = (float*)d_out;

  float* ws  = (float*)d_ws;
  float* up  = ws;                    // 2359296 fp32 (dead after conv1 -> xqb/xkb/qnb overlay)
  float* c1  = up  + 2359296;         // 2359296 fp32 (dead after conv2 -> yvb overlay)
  float* c2  = c1  + 2359296;         // 2359296 fp32
  float* xep = c2  + 2359296;         // 1179648 fp32 (UNUSED now; layout kept for stability)
  float* bsc = xep + 1179648;         // 147456 fp32
  short* ret = (short*)(bsc + 147456);// 9437184 bf16
  int* codes  = (int*)(ret + 9437184);// 147456
  int* sidx   = codes + 147456;       // 147456
  int* hist   = sidx + 147456;        // 73728  [n][code][bb]
  int* bstart = hist + 73728;         // 73728  [n][code][bb]
  short* wpk = (short*)(bstart + 73728); // packed hi/lo weight planes (k_wprep3 layout)
  short* w1H = wpk;
  short* w1L = wpk + 36864;
  short* w2H = wpk + 73728;
  short* w2L = wpk + 110592;
  short* wmH = wpk + 147456;
  short* wmL = wpk + 165888;
  // overlays (write-after-read ordering enforced by launch order)
  short* xqb = (short*)up;            // 1179648 shorts
  short* xkb = xqb + 1179648;         // 1179648 shorts
  float* qnb = (float*)(xkb + 1179648); // 36864 floats
  short* yvb = (short*)c1;            // 2359296 shorts
  (void)in_sizes; (void)n_in; (void)out_size; (void)ws_size;

  k_wprep3<<<dim3((92160 + 255)/256), dim3(256), 0, stream>>>(w1, w2, wm, wpk, hist);
  k_upsample<<<dim3((NB*CIN*HH*WW + 255)/256), dim3(256), 0, stream>>>(x, up);
  k_conv3m<128,false,true><<<dim3(NB*72*2), dim3(256), 0, stream>>>(up, w1H, w1L, b1, c1, 64, 2);
  k_conv3m<128,false,true><<<dim3(NB*72*2), dim3(256), 0, stream>>>(c1, w2H, w2L, b2, c2, 64, 2);
  k_cmhash<<<dim3(NB*144), dim3(256), 0, stream>>>(c2, wmH, wmL, bm, rot, codes, hist, xqb, xkb, qnb);
  k_conv1x1<<<dim3(NB*(LTOK/128)), dim3(256), 0, stream>>>(c2, wa, ba, yvb);
  k_offsets<<<dim3(NB), dim3(256), 0, stream>>>(hist, bstart);
  k_scatter<<<dim3(NB*NSB), dim3(SB), 0, stream>>>(codes, bstart, sidx);
  k_attn<<<dim3(NB*NH*NCHUNK/2), dim3(192), 0, stream>>>(xqb, xkb, qnb, yvb, sidx, ret, bsc);
  k_combine<<<dim3(NB*(LTOK/16)), dim3(256), 0, stream>>>(ret, bsc, c2, out);
}

// Round 12
// 350.770 us; speedup vs baseline: 1.0944x; 1.0944x over previous
//
#include <hip/hip_runtime.h>
#include <math.h>

#define NB 4
#define CIN 64
#define CO 64
#define CM 32
#define H0 48
#define W0 48
#define HH 96
#define WW 96
#define LTOK (HH*WW)     // 9216 tokens per image
#define NH 4
#define NBUCK 64
#define CHUNK 144
#define NCHUNK 64        // LTOK / CHUNK
#define TOT (NH*LTOK)    // 36864
#define SB 512
#define NSB (TOT/SB)     // 72

typedef __attribute__((ext_vector_type(8))) short short8;
typedef __attribute__((ext_vector_type(4))) short short4v;
typedef __attribute__((ext_vector_type(4))) float f32x4;

__device__ __forceinline__ short f2bf(float f) {          // RNE
  union { float f; unsigned u; } v; v.f = f;
  unsigned r = v.u + 0x7fffu + ((v.u >> 16) & 1u);
  return (short)(r >> 16);
}
__device__ __forceinline__ short f2bf_fast(float f) {     // round-half-up (1 add)
  union { float f; unsigned u; } v; v.f = f;
  return (short)((v.u + 0x8000u) >> 16);
}
__device__ __forceinline__ float bf2f(short h) {
  union { float f; unsigned u; } v; v.u = ((unsigned)(unsigned short)h) << 16;
  return v.f;
}
__device__ __forceinline__ short8 ld_b64x2(const short* p) {  // 8B-aligned pair load
  short4v a = *(const short4v*)p;
  short4v b = *(const short4v*)(p+4);
  short8 r; r[0]=a[0];r[1]=a[1];r[2]=a[2];r[3]=a[3];r[4]=b[0];r[5]=b[1];r[6]=b[2];r[7]=b[3];
  return r;
}

// ---------------- bicubic upsample (jax.image.resize, cubic a=-0.5, half-pixel) ----------------
__device__ __forceinline__ void cubic_taps(int o, int insz, int* p, float* w) {
  int j = o >> 1;
  const float B0=-0.0234375f, B1=0.2265625f, B2=0.8671875f, B3=-0.0703125f;
  if ((o & 1) == 0) { p[0]=j-2;p[1]=j-1;p[2]=j;  p[3]=j+1; w[0]=B0;w[1]=B1;w[2]=B2;w[3]=B3; }
  else              { p[0]=j-1;p[1]=j;  p[2]=j+1;p[3]=j+2; w[0]=B3;w[1]=B2;w[2]=B1;w[3]=B0; }
  float s = 0.f;
  #pragma unroll
  for (int a=0;a<4;a++){ if (p[a] < 0 || p[a] >= insz) p[a] = -1; else s += w[a]; }
  float inv = 1.f / s;
  #pragma unroll
  for (int a=0;a<4;a++) w[a] *= inv;
}

__global__ void k_upsample(const float* __restrict__ x, float* __restrict__ up) {
  int i = blockIdx.x*blockDim.x + threadIdx.x;
  if (i >= NB*CIN*HH*WW) return;
  int ox = i % WW; int t = i / WW;
  int oy = t % HH; t /= HH;
  int c = t % CIN; int n = t / CIN;
  int px[4]; float wx[4]; cubic_taps(ox, W0, px, wx);
  int py[4]; float wy[4]; cubic_taps(oy, H0, py, wy);
  const float* src = x + ((size_t)(n*CIN + c))*H0*W0;
  float acc = 0.f;
  #pragma unroll
  for (int a=0;a<4;a++) {
    if (py[a] < 0) continue;
    const float* r = src + py[a]*W0;
    float ra = 0.f;
    #pragma unroll
    for (int b=0;b<4;b++) if (px[b] >= 0) ra = fmaf(wx[b], r[px[b]], ra);
    acc = fmaf(wy[a], ra, acc);
  }
  up[i] = acc;
}

// ---------------- weight prep (all four convs in ONE launch) --------------------------------
// layout: w1H w1L w2H w2L (36864 each) wmH wmL (18432 each) waH waL (4096 each)
__global__ void k_wprep3(const float* __restrict__ w1, const float* __restrict__ w2,
                         const float* __restrict__ wm, const float* __restrict__ wa,
                         short* __restrict__ base) {
  int i = blockIdx.x*blockDim.x + threadIdx.x;
  if (i >= 96256) return;
  if (i >= 92160) {                              // conv_assembly 1x1: [co][ci]
    int j = i - 92160;
    float v = wa[j];
    short hi = f2bf(v);
    base[184320 + j] = hi;
    base[188416 + j] = f2bf(v - bf2f(hi));
    return;
  }
  const float* src; short *dH, *dL; int couts, j;
  if (i < 36864)      { src = w1; couts = 64; j = i;          dH = base;          dL = base + 36864; }
  else if (i < 73728) { src = w2; couts = 64; j = i - 36864;  dH = base + 73728;  dL = base + 110592; }
  else                { src = wm; couts = 32; j = i - 73728;  dH = base + 147456; dL = base + 165888; }
  int ci = j & 63; int t = j >> 6; int co = t % couts; int s = t / couts;
  float v = src[((size_t)(co*64 + ci))*9 + s];
  short hi = f2bf(v);
  dH[j] = hi;
  dL[j] = f2bf(v - bf2f(hi));
}

// ---------------- 3x3 conv as implicit GEMM, K=64 stages, 32-co blocks ----------------------
#define XP 68   // X LDS pitch in shorts (136B: 8B-aligned b64 frags)
#define WP 72   // W LDS pitch in shorts (144B: 16B-aligned b128 frags)
template<int TOKS, bool TMAJ, bool RELU>
__global__ __launch_bounds__(256) void k_conv3m(const float* __restrict__ in,
                          const short* __restrict__ wH, const short* __restrict__ wL,
                          const float* __restrict__ bias, float* __restrict__ out,
                          int couts_tot, int cosplit) {
  int blk = blockIdx.x;              // NB * (LTOK/TOKS) * cosplit
  int ch = blk % cosplit;
  int tb = (blk / cosplit) % (LTOK/TOKS);
  int n  = blk / (cosplit * (LTOK/TOKS));
  int t0 = tb * TOKS;
  int co0 = ch * 32;
  int tid = threadIdx.x;
  int wv = tid >> 6, lane = tid & 63, quad = lane >> 4, l16 = lane & 15;
  __shared__ __align__(16) short XB[TOKS*XP];
  __shared__ __align__(16) short WHs[32*WP];
  __shared__ __align__(16) short WLs[32*WP];
  __shared__ float biasl[32];
  if (tid < 32) biasl[tid] = bias[co0 + tid];
  constexpr int TSH = (TOKS == 128) ? 7 : 6;
  f32x4 acc[2][2];
  #pragma unroll
  for (int a=0;a<2;a++)
    #pragma unroll
    for (int b=0;b<2;b++) acc[a][b] = (f32x4){0.f,0.f,0.f,0.f};

  const float* inb = in + (size_t)n*CIN*LTOK;
  for (int s = 0; s < 9; s++) {
    int dy = s/3 - 1, dx = s%3 - 1;
    __syncthreads();
    #pragma unroll
    for (int it = 0; it < (TOKS*32)/256; it++) {
      int idx = tid + 256*it;
      int tok = idx & (TOKS-1), c = idx >> TSH;
      int t = t0 + tok;
      int y = t / WW, x = t - y*WW;
      int ys = y + dy, xs = x + dx;
      float v0 = 0.f, v1 = 0.f;
      if ((unsigned)ys < HH && (unsigned)xs < WW) {
        const float* p = inb + ((size_t)(2*c))*LTOK + ys*WW + xs;
        v0 = p[0]; v1 = p[LTOK];
      }
      unsigned pk = (unsigned)(unsigned short)f2bf(v0) | (((unsigned)(unsigned short)f2bf(v1)) << 16);
      ((unsigned*)XB)[tok*(XP/2) + c] = pk;
    }
    #pragma unroll
    for (int it = 0; it < 8; it++) {
      int idx = tid + 256*it;
      int plane = idx >> 10, rem = idx & 1023;
      int co = rem >> 5, d = rem & 31;
      const unsigned* srcw = (const unsigned*)(plane ? wL : wH);
      unsigned v = srcw[(size_t)(s*couts_tot + co0 + co)*32 + d];
      unsigned* dst = (unsigned*)(plane ? WLs : WHs);
      dst[co*(WP/2) + d] = v;
    }
    __syncthreads();
    #pragma unroll
    for (int kf = 0; kf < 2; kf++) {
      if (!TMAJ) {
        short8 xf[2];
        #pragma unroll
        for (int nt=0;nt<2;nt++)
          xf[nt] = ld_b64x2(&XB[(wv*32 + nt*16 + l16)*XP + kf*32 + quad*8]);
        #pragma unroll
        for (int mt=0;mt<2;mt++) {
          short8 wh = *(const short8*)&WHs[(mt*16 + l16)*WP + kf*32 + quad*8];
          short8 wl = *(const short8*)&WLs[(mt*16 + l16)*WP + kf*32 + quad*8];
          #pragma unroll
          for (int nt=0;nt<2;nt++) {
            acc[mt][nt] = __builtin_amdgcn_mfma_f32_16x16x32_bf16(wh, xf[nt], acc[mt][nt], 0, 0, 0);
            acc[mt][nt] = __builtin_amdgcn_mfma_f32_16x16x32_bf16(wl, xf[nt], acc[mt][nt], 0, 0, 0);
          }
        }
      } else {
        short8 xf = ld_b64x2(&XB[(wv*16 + l16)*XP + kf*32 + quad*8]);
        #pragma unroll
        for (int nt=0;nt<2;nt++) {
          short8 wh = *(const short8*)&WHs[(nt*16 + l16)*WP + kf*32 + quad*8];
          short8 wl = *(const short8*)&WLs[(nt*16 + l16)*WP + kf*32 + quad*8];
          acc[0][nt] = __builtin_amdgcn_mfma_f32_16x16x32_bf16(xf, wh, acc[0][nt], 0, 0, 0);
          acc[0][nt] = __builtin_amdgcn_mfma_f32_16x16x32_bf16(xf, wl, acc[0][nt], 0, 0, 0);
        }
      }
    }
  }
  if (!TMAJ) {   // D[m=co][n=tok] -> NCHW
    #pragma unroll
    for (int mt=0;mt<2;mt++) {
      #pragma unroll
      for (int nt=0;nt<2;nt++) {
        int tokl = wv*32 + nt*16 + l16;
        #pragma unroll
        for (int reg=0;reg<4;reg++) {
          int col = mt*16 + quad*4 + reg;
          float v = acc[mt][nt][reg] + biasl[col];
          if (RELU) v = fmaxf(v, 0.f);
          out[((size_t)(n*couts_tot + co0 + col))*LTOK + t0 + tokl] = v;
        }
      }
    }
  } else {       // D[m=tok][n=co] -> token-major
    #pragma unroll
    for (int nt=0;nt<2;nt++) {
      int co = nt*16 + l16;
      #pragma unroll
      for (int reg=0;reg<4;reg++) {
        int t = t0 + wv*16 + quad*4 + reg;
        float v = acc[0][nt][reg] + biasl[co];
        if (RELU) v = fmaxf(v, 0.f);
        out[((size_t)n*LTOK + t)*couts_tot + co] = v;
      }
    }
  }
}

// ---------------- 1x1 conv as bf16 MFMA GEMM -> bf16 token-major V [n][t][64] ---------------
// 64 tok x 64 co per block, W split hi/lo, one staging barrier, 16 MFMAs/wave.
__global__ __launch_bounds__(256) void k_conv1x1m(const float* __restrict__ in,
                          const short* __restrict__ wH, const short* __restrict__ wL,
                          const float* __restrict__ bias, short* __restrict__ out) {
  int blk = blockIdx.x;           // NB * 144
  int n  = blk / 144;
  int t0 = (blk % 144) * 64;
  int tid = threadIdx.x;
  int wv = tid >> 6, lane = tid & 63, quad = lane >> 4, l16 = lane & 15;
  __shared__ __align__(16) short XB[64*XP];
  __shared__ __align__(16) short WHs[64*WP];
  __shared__ __align__(16) short WLs[64*WP];
  __shared__ float biasl[64];
  if (tid < 64) biasl[tid] = bias[tid];
  const float* inb = in + (size_t)n*CIN*LTOK;
  #pragma unroll
  for (int it = 0; it < 8; it++) {          // X: 64 tok x 32 ci-pairs
    int idx = tid + 256*it;
    int tok = idx & 63, c = idx >> 6;
    const float* p = inb + ((size_t)(2*c))*LTOK + t0 + tok;
    float v0 = p[0], v1 = p[LTOK];
    unsigned pk = (unsigned)(unsigned short)f2bf(v0) | (((unsigned)(unsigned short)f2bf(v1)) << 16);
    ((unsigned*)XB)[tok*(XP/2) + c] = pk;
  }
  #pragma unroll
  for (int it = 0; it < 16; it++) {         // W hi/lo: 64 co x 32 dwords x 2 planes
    int idx = tid + 256*it;
    int plane = idx >> 11, rem = idx & 2047;
    int co = rem >> 5, d = rem & 31;
    const unsigned* srcw = (const unsigned*)(plane ? wL : wH);
    unsigned v = srcw[(size_t)co*32 + d];
    unsigned* dst = (unsigned*)(plane ? WLs : WHs);
    dst[co*(WP/2) + d] = v;
  }
  __syncthreads();
  f32x4 acc[4];
  #pragma unroll
  for (int i=0;i<4;i++) acc[i] = (f32x4){0.f,0.f,0.f,0.f};
  #pragma unroll
  for (int kf = 0; kf < 2; kf++) {
    short8 xf = ld_b64x2(&XB[(wv*16 + l16)*XP + kf*32 + quad*8]);
    #pragma unroll
    for (int nt=0;nt<4;nt++) {
      short8 wh = *(const short8*)&WHs[(nt*16 + l16)*WP + kf*32 + quad*8];
      short8 wl = *(const short8*)&WLs[(nt*16 + l16)*WP + kf*32 + quad*8];
      acc[nt] = __builtin_amdgcn_mfma_f32_16x16x32_bf16(xf, wh, acc[nt], 0, 0, 0);
      acc[nt] = __builtin_amdgcn_mfma_f32_16x16x32_bf16(xf, wl, acc[nt], 0, 0, 0);
    }
  }
  #pragma unroll
  for (int nt=0;nt<4;nt++) {
    int co = nt*16 + l16;
    #pragma unroll
    for (int reg=0;reg<4;reg++) {
      int t = t0 + wv*16 + quad*4 + reg;
      out[((size_t)n*LTOK + t)*CO + co] = f2bf(acc[nt][reg] + biasl[co]);
    }
  }
}

// ---------------- LSH hash (+ fused token prep in h==0 blocks) ------------------------------
// hist layout: [n][code][bb] so k_offsets reads are per-thread contiguous.
__global__ void k_hash(const float* __restrict__ xe, const float* __restrict__ rot,
                       int* __restrict__ codes, int* __restrict__ hist,
                       short* __restrict__ xqb, short* __restrict__ xkb,
                       float* __restrict__ qnb) {
  int b  = blockIdx.x;
  int n  = b / NSB;
  int bb = b % NSB;
  int j  = bb*SB + threadIdx.x;
  int h  = j / LTOK;             // uniform per block (LTOK = 18*SB)
  int t  = j % LTOK;
  __shared__ float rl[CM][NBUCK/2];
  __shared__ int lh[256];
  for (int e = threadIdx.x; e < 256; e += SB) lh[e] = 0;
  for (int e = threadIdx.x; e < CM*(NBUCK/2); e += SB) {
    int f = e / 32, i = e % 32;
    rl[f][i] = rot[(f*NH + h)*32 + i];
  }
  __syncthreads();
  float q[CM];
  const float4* xr4 = (const float4*)(xe + ((size_t)n*LTOK + t)*CM);
  #pragma unroll
  for (int r = 0; r < 8; r++) {
    float4 v = xr4[r];
    q[4*r+0]=v.x; q[4*r+1]=v.y; q[4*r+2]=v.z; q[4*r+3]=v.w;
  }
  // fused prep: h==0 blocks emit bf16 Q rows, bf16 normalized K rows, norms (once per token)
  if (bb < LTOK/SB) {
    float ssq = 0.f;
    #pragma unroll
    for (int f = 0; f < CM; f++) ssq = fmaf(q[f], q[f], ssq);
    float nrm = sqrtf(ssq);
    float rn = 1.f / fmaxf(nrm, 5e-5f);
    qnb[(size_t)n*LTOK + t] = nrm;
    #pragma unroll
    for (int r = 0; r < 4; r++) {
      short8 q8, k8;
      #pragma unroll
      for (int jj = 0; jj < 8; jj++) { q8[jj] = f2bf(q[8*r+jj]); k8[jj] = f2bf(q[8*r+jj]*rn); }
      *(short8*)&xqb[((size_t)n*LTOK + t)*CM + 8*r] = q8;
      *(short8*)&xkb[((size_t)n*LTOK + t)*CM + 8*r] = k8;
    }
  }
  float bp = -INFINITY, bn = -INFINITY; int ip = 0, inn = 0;
  for (int i = 0; i < 32; i++) {
    float acc = 0.f;
    #pragma unroll
    for (int f = 0; f < CM; f++) acc = fmaf(q[f], rl[f][i], acc);
    if (acc  > bp) { bp = acc;  ip  = i; }
    if (-acc > bn) { bn = -acc; inn = i; }
  }
  int code = (bp >= bn) ? ip : (32 + inn);
  code += h * NBUCK;
  codes[n*TOT + j] = code;
  atomicAdd(&lh[code], 1);
  __syncthreads();
  for (int e = threadIdx.x; e < 256; e += SB) hist[((size_t)(n*256 + e))*NSB + bb] = lh[e];
}

// ---------------- stable counting sort (transposed hist: contiguous per-thread runs) --------
__global__ void k_offsets(const int* __restrict__ hist, int* __restrict__ bstart) {
  int n = blockIdx.x; int c = threadIdx.x;
  const int* hrow = hist + (size_t)(n*256 + c)*NSB;
  int tot = 0;
  for (int b = 0; b < NSB; b++) tot += hrow[b];
  __shared__ int sc[256];
  sc[c] = tot;
  __syncthreads();
  for (int d = 1; d < 256; d <<= 1) {
    int u = (c >= d) ? sc[c-d] : 0;
    __syncthreads();
    sc[c] += u;
    __syncthreads();
  }
  int run = sc[c] - tot;
  int* brow = bstart + (size_t)(n*256 + c)*NSB;
  for (int b = 0; b < NSB; b++) {
    brow[b] = run;
    run += hrow[b];
  }
}

// ballot-based stable rank: rank = #earlier-threads-in-block with same code.
__global__ void k_scatter(const int* __restrict__ codes, const int* __restrict__ bstart,
                          int* __restrict__ sidx) {
  int b = blockIdx.x; int n = b / NSB; int bb = b % NSB;
  int tid = threadIdx.x;
  int j = bb*SB + tid;
  int code = codes[n*TOT + j];
  int wave = tid >> 6, lane = tid & 63;
  __shared__ int wcnt[8][256];
  for (int e = tid; e < 8*256; e += SB) ((int*)wcnt)[e] = 0;
  __syncthreads();
  unsigned long long mask = ~0ULL;
  #pragma unroll
  for (int bit = 0; bit < 8; bit++) {
    unsigned long long bal = __ballot((code >> bit) & 1);
    mask &= ((code >> bit) & 1) ? bal : ~bal;
  }
  unsigned long long lt = (lane == 63) ? 0x7FFFFFFFFFFFFFFFULL : ((1ULL << lane) - 1ULL);
  int rank_w = __popcll(mask & lt);
  if (rank_w == 0) wcnt[wave][code] = __popcll(mask);
  __syncthreads();
  int rank = rank_w;
  for (int w2 = 0; w2 < 8; w2++) {
    if (w2 >= wave) break;
    rank += wcnt[w2][code];
  }
  int pos = bstart[((size_t)(n*256 + code))*NSB + bb] + rank;
  sidx[n*TOT + pos] = j;
}

// ---------------- MFMA bf16 flash attention: 2 chunks/block, batched S -> batched PV --------
// XCD-aware block swizzle: blk&7 ~ XCD slot (round-robin dispatch heuristic); pin each image
// to 2 XCD slots so its ~2.4MB K/Q/V working set stays in one XCD's 4MB L2.
#define PQP 168   // P / V^T pitch in shorts (160 key cols + 8 pad; 16B aligned)
__global__ __launch_bounds__(192,1) void k_attn(const short* __restrict__ xqb,
                       const short* __restrict__ xkb, const float* __restrict__ qnb,
                       const short* __restrict__ yvb, const int* __restrict__ sidx,
                       short* __restrict__ ret, float* __restrict__ bsc) {
  int raw = blockIdx.x;               // 512 = NB*NH*NCHUNK/2
  int xcd = raw & 7;
  int n = xcd >> 1;
  int idx2 = ((raw >> 3) << 1) | (xcd & 1);   // 0..127
  int h = idx2 >> 5;
  int cpair = idx2 & 31;
  const int base = n*TOT + h*LTOK;
  __shared__ __align__(16) short Pq[144*PQP];   // P (bf16), cols 144..159 zero pad
  __shared__ __align__(16) short VbT[64*PQP];   // V^T bf16 [ch][key], cols 144..159 zero pad
  __shared__ int sj[3*CHUNK];
  int tid = threadIdx.x;
  int w = tid >> 6, lane = tid & 63, quad = lane >> 4, l16 = lane & 15;
  const short* xq = xqb + (size_t)n*LTOK*CM;
  const short* xk = xkb + (size_t)n*LTOK*CM;
  const short* yv = yvb + (size_t)n*LTOK*CO;
  const float* qn = qnb + (size_t)n*LTOK;

  // one-time zero of the PV over-read pad cols 144..159 in BOTH P and V^T.
  for (int e = tid; e < 144*8; e += 192) {
    int r = e >> 3, d = e & 7;
    ((unsigned*)Pq)[r*(PQP/2) + 72 + d] = 0u;
  }
  for (int e = tid; e < 64*8; e += 192) {
    int r = e >> 3, d = e & 7;
    ((unsigned*)VbT)[r*(PQP/2) + 72 + d] = 0u;
  }

  for (int ch2 = 0; ch2 < 2; ch2++) {
    int kch = cpair*2 + ch2;
    int kprev = (kch + NCHUNK - 1) & (NCHUNK-1), knext = (kch + 1) & (NCHUNK-1);
    __syncthreads();
    for (int e = tid; e < 3*CHUNK; e += 192) {
      int tt = e / CHUNK, r = e - tt*CHUNK;
      int kk = (tt==0) ? kch : ((tt==1) ? kprev : knext);
      sj[e] = sidx[base + kk*CHUNK + r];
    }
    __syncthreads();
    short8 qfrag[3]; float m_ln[3][4];
    #pragma unroll
    for (int mt=0;mt<3;mt++) {
      int tok = sj[48*w + 16*mt + l16] % LTOK;
      qfrag[mt] = *(const short8*)(xq + (size_t)tok*CM + quad*8);
      #pragma unroll
      for (int r=0;r<4;r++)
        m_ln[mt][r] = qn[sj[48*w + 16*mt + 4*quad + r] % LTOK];
    }
    f32x4 acc[3][4];
    #pragma unroll
    for (int mt=0;mt<3;mt++)
      #pragma unroll
      for (int nt=0;nt<4;nt++) acc[mt][nt] = (f32x4){0.f,0.f,0.f,0.f};
    float sspart[12];
    #pragma unroll
    for (int i=0;i<12;i++) sspart[i]=0.f;

    for (int tt = 0; tt < 3; tt++) {
      __syncthreads();
      #pragma unroll
      for (int it = 0; it < 6; it++) {
        int idx = tid + 192*it;
        int g = idx / CHUNK, key = idx - g*CHUNK;
        int tok = sj[tt*CHUNK + key] % LTOK;
        short8 v = *(const short8*)(yv + (size_t)tok*CO + 8*g);
        #pragma unroll
        for (int i=0;i<8;i++) VbT[(8*g+i)*PQP + key] = v[i];
      }
      __syncthreads();
      int ktok[9];
      #pragma unroll
      for (int nt=0;nt<9;nt++) ktok[nt] = sj[tt*CHUNK + 16*nt + l16] % LTOK;
      #pragma unroll
      for (int nt = 0; nt < 9; nt++) {
        short8 bfr = *(const short8*)(xk + (size_t)ktok[nt]*CM + quad*8);
        f32x4 c[3];
        #pragma unroll
        for (int mt=0;mt<3;mt++)
          c[mt] = __builtin_amdgcn_mfma_f32_16x16x32_bf16(qfrag[mt], bfr, (f32x4){0.f,0.f,0.f,0.f}, 0, 0, 0);
        #pragma unroll
        for (int mt=0;mt<3;mt++) {
          #pragma unroll
          for (int reg=0;reg<4;reg++) {
            float p = __expf(c[mt][reg] - m_ln[mt][reg]);
            sspart[mt*4+reg] += p;
            Pq[(48*w + 16*mt + 4*quad + reg)*PQP + 16*nt + l16] = f2bf_fast(p);
          }
        }
      }
      #pragma unroll
      for (int kf = 0; kf < 5; kf++) {
        short8 afr[3];
        #pragma unroll
        for (int mt=0;mt<3;mt++)
          afr[mt] = *(const short8*)&Pq[(48*w + 16*mt + l16)*PQP + kf*32 + quad*8];
        #pragma unroll
        for (int nt2=0;nt2<4;nt2++) {
          short8 vfr = *(const short8*)&VbT[(16*nt2 + l16)*PQP + kf*32 + quad*8];
          #pragma unroll
          for (int mt=0;mt<3;mt++)
            acc[mt][nt2] = __builtin_amdgcn_mfma_f32_16x16x32_bf16(afr[mt], vfr, acc[mt][nt2], 0, 0, 0);
        }
      }
    }
    #pragma unroll
    for (int i=0;i<12;i++) {
      float v = sspart[i];
      v += __shfl_xor(v, 1); v += __shfl_xor(v, 2);
      v += __shfl_xor(v, 4); v += __shfl_xor(v, 8);
      sspart[i] = v;
    }
    #pragma unroll
    for (int mt=0;mt<3;mt++) {
      #pragma unroll
      for (int reg=0;reg<4;reg++) {
        int row = 48*w + 16*mt + 4*quad + reg;
        int mtok = sj[row];
        float ssum = sspart[mt*4+reg];
        float inv = 1.f / ssum;
        short* rp = ret + ((size_t)n*TOT + mtok)*CO;
        #pragma unroll
        for (int nt2=0;nt2<4;nt2++) rp[16*nt2 + l16] = f2bf(acc[mt][nt2][reg] * inv);
        if (l16 == 0) bsc[(size_t)n*TOT + mtok] = m_ln[mt][reg] + logf(ssum);
      }
    }
  }
}

// ---------------- combine 4 hash rounds (softmax over bscore) + residual, NCHW out ----------
__global__ void k_combine(const short* __restrict__ ret, const float* __restrict__ bsc,
                          const float* __restrict__ c2, float* __restrict__ out) {
  int blk = blockIdx.x;                 // NB * (LTOK/16)
  int n  = blk / (LTOK/16);
  int t0 = (blk % (LTOK/16)) * 16;
  __shared__ float rl[NH][16][CO+1];
  __shared__ float pw[NH][16];
  int tid = threadIdx.x;
  for (int h = 0; h < NH; h++)
    for (int e = tid; e < 16*CO; e += 256) {
      int tl = e >> 6, f = e & 63;
      rl[h][tl][f] = bf2f(ret[((size_t)n*TOT + h*LTOK + t0 + tl)*CO + f]);
    }
  if (tid < 16) {
    float b0[NH]; float mm = -INFINITY;
    #pragma unroll
    for (int h = 0; h < NH; h++) { b0[h] = bsc[(size_t)n*TOT + h*LTOK + t0 + tid]; mm = fmaxf(mm, b0[h]); }
    float s = 0.f;
    #pragma unroll
    for (int h = 0; h < NH; h++) { b0[h] = __expf(b0[h] - mm); s += b0[h]; }
    float inv = 1.f / s;
    #pragma unroll
    for (int h = 0; h < NH; h++) pw[h][tid] = b0[h] * inv;
  }
  __syncthreads();
  int tl = tid & 15;
  int cog = tid >> 4;
  #pragma unroll
  for (int cc = 0; cc < 4; cc++) {
    int co = cog + 16*cc;
    size_t oi = ((size_t)(n*CO + co))*LTOK + t0 + tl;
    float a = c2[oi];
    #pragma unroll
    for (int h = 0; h < NH; h++) a = fmaf(pw[h][tl], rl[h][tl][co], a);
    out[oi] = a;
  }
}

extern "C" void kernel_launch(void* const* d_in, const int* in_sizes, int n_in,
                              void* d_out, int out_size, void* d_ws, size_t ws_size,
                              hipStream_t stream) {
  const float* x   = (const float*)d_in[0];
  const float* w1  = (const float*)d_in[1];
  const float* b1  = (const float*)d_in[2];
  const float* w2  = (const float*)d_in[3];
  const float* b2  = (const float*)d_in[4];
  const float* wm  = (const float*)d_in[5];
  const float* bm  = (const float*)d_in[6];
  const float* wa  = (const float*)d_in[7];
  const float* ba  = (const float*)d_in[8];
  const float* rot = (const float*)d_in[9];
  float* out = (float*)d_out;

  float* ws  = (float*)d_ws;
  float* up  = ws;                    // 2359296 fp32 (dead after conv1 -> xqb/xkb/qnb overlay)
  float* c1  = up  + 2359296;         // 2359296 fp32 (dead after conv2 -> yvb overlay)
  float* c2  = c1  + 2359296;         // 2359296 fp32
  float* xep = c2  + 2359296;         // 1179648 fp32 [n][t][32] (conv_match out, hash source)
  float* bsc = xep + 1179648;         // 147456 fp32
  short* ret = (short*)(bsc + 147456);// 9437184 bf16
  int* codes  = (int*)(ret + 9437184);// 147456
  int* sidx   = codes + 147456;       // 147456
  int* hist   = sidx + 147456;        // 73728  [n][code][bb]
  int* bstart = hist + 73728;         // 73728  [n][code][bb]
  short* wpk = (short*)(bstart + 73728); // packed hi/lo weight planes (k_wprep3 layout)
  short* w1H = wpk;
  short* w1L = wpk + 36864;
  short* w2H = wpk + 73728;
  short* w2L = wpk + 110592;
  short* wmH = wpk + 147456;
  short* wmL = wpk + 165888;
  short* waH = wpk + 184320;
  short* waL = wpk + 188416;
  // overlays (write-after-read ordering enforced by launch order)
  short* xqb = (short*)up;            // 1179648 shorts
  short* xkb = xqb + 1179648;         // 1179648 shorts
  float* qnb = (float*)(xkb + 1179648); // 36864 floats
  short* yvb = (short*)c1;            // 2359296 shorts
  (void)in_sizes; (void)n_in; (void)out_size; (void)ws_size;

  k_wprep3<<<dim3((96256 + 255)/256), dim3(256), 0, stream>>>(w1, w2, wm, wa, wpk);
  k_upsample<<<dim3((NB*CIN*HH*WW + 255)/256), dim3(256), 0, stream>>>(x, up);
  k_conv3m<128,false,true><<<dim3(NB*72*2), dim3(256), 0, stream>>>(up, w1H, w1L, b1, c1, 64, 2);
  k_conv3m<128,false,true><<<dim3(NB*72*2), dim3(256), 0, stream>>>(c1, w2H, w2L, b2, c2, 64, 2);
  k_conv3m<64,true,false><<<dim3(NB*144), dim3(256), 0, stream>>>(c2, wmH, wmL, bm, xep, 32, 1);
  k_conv1x1m<<<dim3(NB*144), dim3(256), 0, stream>>>(c2, waH, waL, ba, yvb);
  k_hash<<<dim3(NB*NSB), dim3(SB), 0, stream>>>(xep, rot, codes, hist, xqb, xkb, qnb);
  k_offsets<<<dim3(NB), dim3(256), 0, stream>>>(hist, bstart);
  k_scatter<<<dim3(NB*NSB), dim3(SB), 0, stream>>>(codes, bstart, sidx);
  k_attn<<<dim3(NB*NH*NCHUNK/2), dim3(192), 0, stream>>>(xqb, xkb, qnb, yvb, sidx, ret, bsc);
  k_combine<<<dim3(NB*(LTOK/16)), dim3(256), 0, stream>>>(ret, bsc, c2, out);
}

// Round 14
// 299.534 us; speedup vs baseline: 1.2816x; 1.1711x over previous
//
#include <hip/hip_runtime.h>
#include <math.h>

#define NB 4
#define CIN 64
#define CO 64
#define CM 32
#define H0 48
#define W0 48
#define HH 96
#define WW 96
#define LTOK (HH*WW)     // 9216 tokens per image
#define NH 4
#define NBUCK 64
#define CHUNK 144
#define NCHUNK 64        // LTOK / CHUNK
#define TOT (NH*LTOK)    // 36864
#define SB 512
#define NSB (TOT/SB)     // 72

typedef __attribute__((ext_vector_type(8))) short short8;
typedef __attribute__((ext_vector_type(4))) short short4v;
typedef __attribute__((ext_vector_type(4))) float f32x4;

__device__ __forceinline__ short f2bf(float f) {          // RNE
  union { float f; unsigned u; } v; v.f = f;
  unsigned r = v.u + 0x7fffu + ((v.u >> 16) & 1u);
  return (short)(r >> 16);
}
__device__ __forceinline__ unsigned packbf(float a, float b) {
  return (unsigned)(unsigned short)f2bf(a) | (((unsigned)(unsigned short)f2bf(b)) << 16);
}
__device__ __forceinline__ short f2bf_fast(float f) {     // round-half-up (1 add)
  union { float f; unsigned u; } v; v.f = f;
  return (short)((v.u + 0x8000u) >> 16);
}
__device__ __forceinline__ float bf2f(short h) {
  union { float f; unsigned u; } v; v.u = ((unsigned)(unsigned short)h) << 16;
  return v.f;
}
__device__ __forceinline__ short8 ld_b64x2(const short* p) {  // 8B-aligned pair load
  short4v a = *(const short4v*)p;
  short4v b = *(const short4v*)(p+4);
  short8 r; r[0]=a[0];r[1]=a[1];r[2]=a[2];r[3]=a[3];r[4]=b[0];r[5]=b[1];r[6]=b[2];r[7]=b[3];
  return r;
}

// ---------------- bicubic upsample -> bf16 channel-pair-interleaved [n][ci/2][tok]x2 --------
__device__ __forceinline__ void cubic_taps(int o, int insz, int* p, float* w) {
  int j = o >> 1;
  const float B0=-0.0234375f, B1=0.2265625f, B2=0.8671875f, B3=-0.0703125f;
  if ((o & 1) == 0) { p[0]=j-2;p[1]=j-1;p[2]=j;  p[3]=j+1; w[0]=B0;w[1]=B1;w[2]=B2;w[3]=B3; }
  else              { p[0]=j-1;p[1]=j;  p[2]=j+1;p[3]=j+2; w[0]=B3;w[1]=B2;w[2]=B1;w[3]=B0; }
  float s = 0.f;
  #pragma unroll
  for (int a=0;a<4;a++){ if (p[a] < 0 || p[a] >= insz) p[a] = -1; else s += w[a]; }
  float inv = 1.f / s;
  #pragma unroll
  for (int a=0;a<4;a++) w[a] *= inv;
}

__global__ void k_upsample(const float* __restrict__ x, unsigned* __restrict__ upb) {
  int i = blockIdx.x*blockDim.x + threadIdx.x;   // NB*32*HH*WW: 2 channels per thread
  if (i >= NB*32*HH*WW) return;
  int ox = i % WW; int t = i / WW;
  int oy = t % HH; t /= HH;
  int c2 = t % 32; int n = t / 32;
  int px[4]; float wx[4]; cubic_taps(ox, W0, px, wx);
  int py[4]; float wy[4]; cubic_taps(oy, H0, py, wy);
  float a01[2];
  #pragma unroll
  for (int cc = 0; cc < 2; cc++) {
    const float* src = x + ((size_t)(n*CIN + 2*c2 + cc))*H0*W0;
    float acc = 0.f;
    #pragma unroll
    for (int a=0;a<4;a++) {
      if (py[a] < 0) continue;
      const float* r = src + py[a]*W0;
      float ra = 0.f;
      #pragma unroll
      for (int b=0;b<4;b++) if (px[b] >= 0) ra = fmaf(wx[b], r[px[b]], ra);
      acc = fmaf(wy[a], ra, acc);
    }
    a01[cc] = acc;
  }
  upb[((size_t)(n*32 + c2))*LTOK + oy*WW + ox] = packbf(a01[0], a01[1]);
}

// ---------------- weight prep (all four convs in ONE launch) --------------------------------
// layout: w1H w1L w2H w2L (36864 each) wmH wmL (18432 each) waH waL (4096 each)
__global__ void k_wprep3(const float* __restrict__ w1, const float* __restrict__ w2,
                         const float* __restrict__ wm, const float* __restrict__ wa,
                         short* __restrict__ base) {
  int i = blockIdx.x*blockDim.x + threadIdx.x;
  if (i >= 96256) return;
  if (i >= 92160) {                              // conv_assembly 1x1: [co][ci]
    int j = i - 92160;
    float v = wa[j];
    short hi = f2bf(v);
    base[184320 + j] = hi;
    base[188416 + j] = f2bf(v - bf2f(hi));
    return;
  }
  const float* src; short *dH, *dL; int couts, j;
  if (i < 36864)      { src = w1; couts = 64; j = i;          dH = base;          dL = base + 36864; }
  else if (i < 73728) { src = w2; couts = 64; j = i - 36864;  dH = base + 73728;  dL = base + 110592; }
  else                { src = wm; couts = 32; j = i - 73728;  dH = base + 147456; dL = base + 165888; }
  int ci = j & 63; int t = j >> 6; int co = t % couts; int s = t / couts;
  float v = src[((size_t)(co*64 + ci))*9 + s];
  short hi = f2bf(v);
  dH[j] = hi;
  dL[j] = f2bf(v - bf2f(hi));
}

// ---------------- 3x3 conv as implicit GEMM, 64-token tiles, bf16-pair input ----------------
// Input is pre-converted bf16 (channel-pair dwords): staging = 1 dword load/task, 0 converts.
#define XP 68   // X LDS pitch in shorts (136B: 8B-aligned b64 frags)
#define WP 72   // W LDS pitch in shorts (144B: 16B-aligned b128 frags)
template<bool TMAJ, bool RELU, bool WF, bool WB>
__global__ __launch_bounds__(256) void k_conv3m(const unsigned* __restrict__ in,
                          const short* __restrict__ wH, const short* __restrict__ wL,
                          const float* __restrict__ bias, float* __restrict__ outF,
                          unsigned* __restrict__ outB, int couts_tot, int cosplit) {
  int blk = blockIdx.x;              // NB * 144 * cosplit
  int ch = blk % cosplit;
  int tb = (blk / cosplit) % 144;
  int n  = blk / (cosplit * 144);
  int t0 = tb * 64;
  int co0 = ch * 32;
  int tid = threadIdx.x;
  int wv = tid >> 6, lane = tid & 63, quad = lane >> 4, l16 = lane & 15;
  __shared__ __align__(16) short XB[64*XP];
  __shared__ __align__(16) short WHs[32*WP];
  __shared__ __align__(16) short WLs[32*WP];
  __shared__ float biasl[32];
  if (tid < 32) biasl[tid] = bias[co0 + tid];
  f32x4 acc[2];
  acc[0] = (f32x4){0.f,0.f,0.f,0.f}; acc[1] = (f32x4){0.f,0.f,0.f,0.f};

  const unsigned* inb = in + (size_t)n*32*LTOK;
  for (int s = 0; s < 9; s++) {
    int dy = s/3 - 1, dx = s%3 - 1;
    __syncthreads();
    // ---- stage X: 64 tok x 32 ci-pair dwords (2048 tasks, 8/thread) ----
    #pragma unroll
    for (int it = 0; it < 8; it++) {
      int idx = tid + 256*it;
      int tok = idx & 63, c = idx >> 6;
      int t = t0 + tok;
      int y = t / WW, x = t - y*WW;
      int ys = y + dy, xs = x + dx;
      unsigned pk = 0;
      if ((unsigned)ys < HH && (unsigned)xs < WW)
        pk = inb[(size_t)c*LTOK + ys*WW + xs];
      ((unsigned*)XB)[tok*(XP/2) + c] = pk;
    }
    // ---- stage W hi+lo: 32 co x 64 ci (2048 dwords) ----
    #pragma unroll
    for (int it = 0; it < 8; it++) {
      int idx = tid + 256*it;
      int plane = idx >> 10, rem = idx & 1023;
      int co = rem >> 5, d = rem & 31;
      const unsigned* srcw = (const unsigned*)(plane ? wL : wH);
      unsigned v = srcw[(size_t)(s*couts_tot + co0 + co)*32 + d];
      unsigned* dst = (unsigned*)(plane ? WLs : WHs);
      dst[co*(WP/2) + d] = v;
    }
    __syncthreads();
    #pragma unroll
    for (int kf = 0; kf < 2; kf++) {
      short8 xf = ld_b64x2(&XB[(wv*16 + l16)*XP + kf*32 + quad*8]);
      if (!TMAJ) {
        // D[m=co][n=tok]: A = W (hi then lo), B = X
        #pragma unroll
        for (int mt=0;mt<2;mt++) {
          short8 wh = *(const short8*)&WHs[(mt*16 + l16)*WP + kf*32 + quad*8];
          short8 wl = *(const short8*)&WLs[(mt*16 + l16)*WP + kf*32 + quad*8];
          acc[mt] = __builtin_amdgcn_mfma_f32_16x16x32_bf16(wh, xf, acc[mt], 0, 0, 0);
          acc[mt] = __builtin_amdgcn_mfma_f32_16x16x32_bf16(wl, xf, acc[mt], 0, 0, 0);
        }
      } else {
        // D[m=tok][n=co]: A = X, B = W
        #pragma unroll
        for (int nt=0;nt<2;nt++) {
          short8 wh = *(const short8*)&WHs[(nt*16 + l16)*WP + kf*32 + quad*8];
          short8 wl = *(const short8*)&WLs[(nt*16 + l16)*WP + kf*32 + quad*8];
          acc[nt] = __builtin_amdgcn_mfma_f32_16x16x32_bf16(xf, wh, acc[nt], 0, 0, 0);
          acc[nt] = __builtin_amdgcn_mfma_f32_16x16x32_bf16(xf, wl, acc[nt], 0, 0, 0);
        }
      }
    }
  }
  if (!TMAJ) {
    int tokl = wv*16 + l16;
    #pragma unroll
    for (int mt=0;mt<2;mt++) {
      float v[4];
      #pragma unroll
      for (int reg=0;reg<4;reg++) {
        int col = mt*16 + quad*4 + reg;
        v[reg] = acc[mt][reg] + biasl[col];
        if (RELU) v[reg] = fmaxf(v[reg], 0.f);
      }
      int colb = mt*16 + quad*4;
      if (WF) {
        #pragma unroll
        for (int reg=0;reg<4;reg++)
          outF[((size_t)(n*couts_tot + co0 + colb + reg))*LTOK + t0 + tokl] = v[reg];
      }
      if (WB) {
        // FIX(R13): batch offset n*(couts_tot/2) was missing -> all images clobbered image 0.
        size_t nb = (size_t)n*(couts_tot >> 1);
        outB[(nb + ((co0 + colb) >> 1))*LTOK + t0 + tokl]     = packbf(v[0], v[1]);
        outB[(nb + ((co0 + colb + 2) >> 1))*LTOK + t0 + tokl] = packbf(v[2], v[3]);
      }
    }
  } else {       // fp32 token-major (conv_match -> xep)
    #pragma unroll
    for (int nt=0;nt<2;nt++) {
      int co = nt*16 + l16;
      #pragma unroll
      for (int reg=0;reg<4;reg++) {
        int t = t0 + wv*16 + quad*4 + reg;
        float v = acc[nt][reg] + biasl[co];
        if (RELU) v = fmaxf(v, 0.f);
        outF[((size_t)n*LTOK + t)*couts_tot + co] = v;
      }
    }
  }
}

// ---------------- 1x1 conv as bf16 MFMA GEMM (bf16-pair input) -> bf16 V [n][t][64] ---------
__global__ __launch_bounds__(256) void k_conv1x1m(const unsigned* __restrict__ in,
                          const short* __restrict__ wH, const short* __restrict__ wL,
                          const float* __restrict__ bias, short* __restrict__ out) {
  int blk = blockIdx.x;           // NB * 144
  int n  = blk / 144;
  int t0 = (blk % 144) * 64;
  int tid = threadIdx.x;
  int wv = tid >> 6, lane = tid & 63, quad = lane >> 4, l16 = lane & 15;
  __shared__ __align__(16) short XB[64*XP];
  __shared__ __align__(16) short WHs[64*WP];
  __shared__ __align__(16) short WLs[64*WP];
  __shared__ float biasl[64];
  if (tid < 64) biasl[tid] = bias[tid];
  const unsigned* inb = in + (size_t)n*32*LTOK;
  #pragma unroll
  for (int it = 0; it < 8; it++) {          // X: 64 tok x 32 ci-pair dwords
    int idx = tid + 256*it;
    int tok = idx & 63, c = idx >> 6;
    ((unsigned*)XB)[tok*(XP/2) + c] = inb[(size_t)c*LTOK + t0 + tok];
  }
  #pragma unroll
  for (int it = 0; it < 16; it++) {         // W hi/lo: 64 co x 32 dwords x 2 planes
    int idx = tid + 256*it;
    int plane = idx >> 11, rem = idx & 2047;
    int co = rem >> 5, d = rem & 31;
    const unsigned* srcw = (const unsigned*)(plane ? wL : wH);
    unsigned v = srcw[(size_t)co*32 + d];
    unsigned* dst = (unsigned*)(plane ? WLs : WHs);
    dst[co*(WP/2) + d] = v;
  }
  __syncthreads();
  f32x4 acc[4];
  #pragma unroll
  for (int i=0;i<4;i++) acc[i] = (f32x4){0.f,0.f,0.f,0.f};
  #pragma unroll
  for (int kf = 0; kf < 2; kf++) {
    short8 xf = ld_b64x2(&XB[(wv*16 + l16)*XP + kf*32 + quad*8]);
    #pragma unroll
    for (int nt=0;nt<4;nt++) {
      short8 wh = *(const short8*)&WHs[(nt*16 + l16)*WP + kf*32 + quad*8];
      short8 wl = *(const short8*)&WLs[(nt*16 + l16)*WP + kf*32 + quad*8];
      acc[nt] = __builtin_amdgcn_mfma_f32_16x16x32_bf16(xf, wh, acc[nt], 0, 0, 0);
      acc[nt] = __builtin_amdgcn_mfma_f32_16x16x32_bf16(xf, wl, acc[nt], 0, 0, 0);
    }
  }
  #pragma unroll
  for (int nt=0;nt<4;nt++) {
    int co = nt*16 + l16;
    #pragma unroll
    for (int reg=0;reg<4;reg++) {
      int t = t0 + wv*16 + quad*4 + reg;
      out[((size_t)n*LTOK + t)*CO + co] = f2bf(acc[nt][reg] + biasl[co]);
    }
  }
}

// ---------------- LSH hash (+ fused token prep in h==0 blocks) ------------------------------
// hist layout: [n][code][bb] so k_offsets reads are per-thread contiguous.
__global__ void k_hash(const float* __restrict__ xe, const float* __restrict__ rot,
                       int* __restrict__ codes, int* __restrict__ hist,
                       short* __restrict__ xqb, short* __restrict__ xkb,
                       float* __restrict__ qnb) {
  int b  = blockIdx.x;
  int n  = b / NSB;
  int bb = b % NSB;
  int j  = bb*SB + threadIdx.x;
  int h  = j / LTOK;             // uniform per block (LTOK = 18*SB)
  int t  = j % LTOK;
  __shared__ float rl[CM][NBUCK/2];
  __shared__ int lh[256];
  for (int e = threadIdx.x; e < 256; e += SB) lh[e] = 0;
  for (int e = threadIdx.x; e < CM*(NBUCK/2); e += SB) {
    int f = e / 32, i = e % 32;
    rl[f][i] = rot[(f*NH + h)*32 + i];
  }
  __syncthreads();
  float q[CM];
  const float4* xr4 = (const float4*)(xe + ((size_t)n*LTOK + t)*CM);
  #pragma unroll
  for (int r = 0; r < 8; r++) {
    float4 v = xr4[r];
    q[4*r+0]=v.x; q[4*r+1]=v.y; q[4*r+2]=v.z; q[4*r+3]=v.w;
  }
  // fused prep: h==0 blocks emit bf16 Q rows, bf16 normalized K rows, norms (once per token)
  if (bb < LTOK/SB) {
    float ssq = 0.f;
    #pragma unroll
    for (int f = 0; f < CM; f++) ssq = fmaf(q[f], q[f], ssq);
    float nrm = sqrtf(ssq);
    float rn = 1.f / fmaxf(nrm, 5e-5f);
    qnb[(size_t)n*LTOK + t] = nrm;
    #pragma unroll
    for (int r = 0; r < 4; r++) {
      short8 q8, k8;
      #pragma unroll
      for (int jj = 0; jj < 8; jj++) { q8[jj] = f2bf(q[8*r+jj]); k8[jj] = f2bf(q[8*r+jj]*rn); }
      *(short8*)&xqb[((size_t)n*LTOK + t)*CM + 8*r] = q8;
      *(short8*)&xkb[((size_t)n*LTOK + t)*CM + 8*r] = k8;
    }
  }
  float bp = -INFINITY, bn = -INFINITY; int ip = 0, inn = 0;
  for (int i = 0; i < 32; i++) {
    float acc = 0.f;
    #pragma unroll
    for (int f = 0; f < CM; f++) acc = fmaf(q[f], rl[f][i], acc);
    if (acc  > bp) { bp = acc;  ip  = i; }
    if (-acc > bn) { bn = -acc; inn = i; }
  }
  int code = (bp >= bn) ? ip : (32 + inn);
  code += h * NBUCK;
  codes[n*TOT + j] = code;
  atomicAdd(&lh[code], 1);
  __syncthreads();
  for (int e = threadIdx.x; e < 256; e += SB) hist[((size_t)(n*256 + e))*NSB + bb] = lh[e];
}

// ---------------- stable counting sort (transposed hist: contiguous per-thread runs) --------
__global__ void k_offsets(const int* __restrict__ hist, int* __restrict__ bstart) {
  int n = blockIdx.x; int c = threadIdx.x;
  const int* hrow = hist + (size_t)(n*256 + c)*NSB;
  int tot = 0;
  for (int b = 0; b < NSB; b++) tot += hrow[b];
  __shared__ int sc[256];
  sc[c] = tot;
  __syncthreads();
  for (int d = 1; d < 256; d <<= 1) {
    int u = (c >= d) ? sc[c-d] : 0;
    __syncthreads();
    sc[c] += u;
    __syncthreads();
  }
  int run = sc[c] - tot;
  int* brow = bstart + (size_t)(n*256 + c)*NSB;
  for (int b = 0; b < NSB; b++) {
    brow[b] = run;
    run += hrow[b];
  }
}

// ballot-based stable rank: rank = #earlier-threads-in-block with same code.
__global__ void k_scatter(const int* __restrict__ codes, const int* __restrict__ bstart,
                          int* __restrict__ sidx) {
  int b = blockIdx.x; int n = b / NSB; int bb = b % NSB;
  int tid = threadIdx.x;
  int j = bb*SB + tid;
  int code = codes[n*TOT + j];
  int wave = tid >> 6, lane = tid & 63;
  __shared__ int wcnt[8][256];
  for (int e = tid; e < 8*256; e += SB) ((int*)wcnt)[e] = 0;
  __syncthreads();
  unsigned long long mask = ~0ULL;
  #pragma unroll
  for (int bit = 0; bit < 8; bit++) {
    unsigned long long bal = __ballot((code >> bit) & 1);
    mask &= ((code >> bit) & 1) ? bal : ~bal;
  }
  unsigned long long lt = (lane == 63) ? 0x7FFFFFFFFFFFFFFFULL : ((1ULL << lane) - 1ULL);
  int rank_w = __popcll(mask & lt);
  if (rank_w == 0) wcnt[wave][code] = __popcll(mask);
  __syncthreads();
  int rank = rank_w;
  for (int w2 = 0; w2 < 8; w2++) {
    if (w2 >= wave) break;
    rank += wcnt[w2][code];
  }
  int pos = bstart[((size_t)(n*256 + code))*NSB + bb] + rank;
  sidx[n*TOT + pos] = j;
}

// ---------------- MFMA bf16 flash attention: 2 chunks/block, batched S -> batched PV --------
// XCD-aware block swizzle: blk&7 ~ XCD slot; pin each image to 2 slots for L2 locality.
#define PQP 168   // P / V^T pitch in shorts (160 key cols + 8 pad; 16B aligned)
__global__ __launch_bounds__(192,1) void k_attn(const short* __restrict__ xqb,
                       const short* __restrict__ xkb, const float* __restrict__ qnb,
                       const short* __restrict__ yvb, const int* __restrict__ sidx,
                       short* __restrict__ ret, float* __restrict__ bsc) {
  int raw = blockIdx.x;               // 512 = NB*NH*NCHUNK/2
  int xcd = raw & 7;
  int n = xcd >> 1;
  int idx2 = ((raw >> 3) << 1) | (xcd & 1);   // 0..127
  int h = idx2 >> 5;
  int cpair = idx2 & 31;
  const int base = n*TOT + h*LTOK;
  __shared__ __align__(16) short Pq[144*PQP];   // P (bf16), cols 144..159 zero pad
  __shared__ __align__(16) short VbT[64*PQP];   // V^T bf16 [ch][key], cols 144..159 zero pad
  __shared__ int sj[3*CHUNK];
  int tid = threadIdx.x;
  int w = tid >> 6, lane = tid & 63, quad = lane >> 4, l16 = lane & 15;
  const short* xq = xqb + (size_t)n*LTOK*CM;
  const short* xk = xkb + (size_t)n*LTOK*CM;
  const short* yv = yvb + (size_t)n*LTOK*CO;
  const float* qn = qnb + (size_t)n*LTOK;

  // one-time zero of the PV over-read pad cols 144..159 in BOTH P and V^T.
  for (int e = tid; e < 144*8; e += 192) {
    int r = e >> 3, d = e & 7;
    ((unsigned*)Pq)[r*(PQP/2) + 72 + d] = 0u;
  }
  for (int e = tid; e < 64*8; e += 192) {
    int r = e >> 3, d = e & 7;
    ((unsigned*)VbT)[r*(PQP/2) + 72 + d] = 0u;
  }

  for (int ch2 = 0; ch2 < 2; ch2++) {
    int kch = cpair*2 + ch2;
    int kprev = (kch + NCHUNK - 1) & (NCHUNK-1), knext = (kch + 1) & (NCHUNK-1);
    __syncthreads();
    for (int e = tid; e < 3*CHUNK; e += 192) {
      int tt = e / CHUNK, r = e - tt*CHUNK;
      int kk = (tt==0) ? kch : ((tt==1) ? kprev : knext);
      sj[e] = sidx[base + kk*CHUNK + r];
    }
    __syncthreads();
    short8 qfrag[3]; float m_ln[3][4];
    #pragma unroll
    for (int mt=0;mt<3;mt++) {
      int tok = sj[48*w + 16*mt + l16] % LTOK;
      qfrag[mt] = *(const short8*)(xq + (size_t)tok*CM + quad*8);
      #pragma unroll
      for (int r=0;r<4;r++)
        m_ln[mt][r] = qn[sj[48*w + 16*mt + 4*quad + r] % LTOK];
    }
    f32x4 acc[3][4];
    #pragma unroll
    for (int mt=0;mt<3;mt++)
      #pragma unroll
      for (int nt=0;nt<4;nt++) acc[mt][nt] = (f32x4){0.f,0.f,0.f,0.f};
    float sspart[12];
    #pragma unroll
    for (int i=0;i<12;i++) sspart[i]=0.f;

    for (int tt = 0; tt < 3; tt++) {
      __syncthreads();
      #pragma unroll
      for (int it = 0; it < 6; it++) {
        int idx = tid + 192*it;
        int g = idx / CHUNK, key = idx - g*CHUNK;
        int tok = sj[tt*CHUNK + key] % LTOK;
        short8 v = *(const short8*)(yv + (size_t)tok*CO + 8*g);
        #pragma unroll
        for (int i=0;i<8;i++) VbT[(8*g+i)*PQP + key] = v[i];
      }
      __syncthreads();
      int ktok[9];
      #pragma unroll
      for (int nt=0;nt<9;nt++) ktok[nt] = sj[tt*CHUNK + 16*nt + l16] % LTOK;
      #pragma unroll
      for (int nt = 0; nt < 9; nt++) {
        short8 bfr = *(const short8*)(xk + (size_t)ktok[nt]*CM + quad*8);
        f32x4 c[3];
        #pragma unroll
        for (int mt=0;mt<3;mt++)
          c[mt] = __builtin_amdgcn_mfma_f32_16x16x32_bf16(qfrag[mt], bfr, (f32x4){0.f,0.f,0.f,0.f}, 0, 0, 0);
        #pragma unroll
        for (int mt=0;mt<3;mt++) {
          #pragma unroll
          for (int reg=0;reg<4;reg++) {
            float p = __expf(c[mt][reg] - m_ln[mt][reg]);
            sspart[mt*4+reg] += p;
            Pq[(48*w + 16*mt + 4*quad + reg)*PQP + 16*nt + l16] = f2bf_fast(p);
          }
        }
      }
      #pragma unroll
      for (int kf = 0; kf < 5; kf++) {
        short8 afr[3];
        #pragma unroll
        for (int mt=0;mt<3;mt++)
          afr[mt] = *(const short8*)&Pq[(48*w + 16*mt + l16)*PQP + kf*32 + quad*8];
        #pragma unroll
        for (int nt2=0;nt2<4;nt2++) {
          short8 vfr = *(const short8*)&VbT[(16*nt2 + l16)*PQP + kf*32 + quad*8];
          #pragma unroll
          for (int mt=0;mt<3;mt++)
            acc[mt][nt2] = __builtin_amdgcn_mfma_f32_16x16x32_bf16(afr[mt], vfr, acc[mt][nt2], 0, 0, 0);
        }
      }
    }
    #pragma unroll
    for (int i=0;i<12;i++) {
      float v = sspart[i];
      v += __shfl_xor(v, 1); v += __shfl_xor(v, 2);
      v += __shfl_xor(v, 4); v += __shfl_xor(v, 8);
      sspart[i] = v;
    }
    #pragma unroll
    for (int mt=0;mt<3;mt++) {
      #pragma unroll
      for (int reg=0;reg<4;reg++) {
        int row = 48*w + 16*mt + 4*quad + reg;
        int mtok = sj[row];
        float ssum = sspart[mt*4+reg];
        float inv = 1.f / ssum;
        short* rp = ret + ((size_t)n*TOT + mtok)*CO;
        #pragma unroll
        for (int nt2=0;nt2<4;nt2++) rp[16*nt2 + l16] = f2bf(acc[mt][nt2][reg] * inv);
        if (l16 == 0) bsc[(size_t)n*TOT + mtok] = m_ln[mt][reg] + logf(ssum);
      }
    }
  }
}

// ---------------- combine 4 hash rounds (softmax over bscore) + residual, NCHW out ----------
__global__ void k_combine(const short* __restrict__ ret, const float* __restrict__ bsc,
                          const float* __restrict__ c2, float* __restrict__ out) {
  int blk = blockIdx.x;                 // NB * (LTOK/16)
  int n  = blk / (LTOK/16);
  int t0 = (blk % (LTOK/16)) * 16;
  __shared__ float rl[NH][16][CO+1];
  __shared__ float pw[NH][16];
  int tid = threadIdx.x;
  for (int h = 0; h < NH; h++)
    for (int e = tid; e < 16*CO; e += 256) {
      int tl = e >> 6, f = e & 63;
      rl[h][tl][f] = bf2f(ret[((size_t)n*TOT + h*LTOK + t0 + tl)*CO + f]);
    }
  if (tid < 16) {
    float b0[NH]; float mm = -INFINITY;
    #pragma unroll
    for (int h = 0; h < NH; h++) { b0[h] = bsc[(size_t)n*TOT + h*LTOK + t0 + tid]; mm = fmaxf(mm, b0[h]); }
    float s = 0.f;
    #pragma unroll
    for (int h = 0; h < NH; h++) { b0[h] = __expf(b0[h] - mm); s += b0[h]; }
    float inv = 1.f / s;
    #pragma unroll
    for (int h = 0; h < NH; h++) pw[h][tid] = b0[h] * inv;
  }
  __syncthreads();
  int tl = tid & 15;
  int cog = tid >> 4;
  #pragma unroll
  for (int cc = 0; cc < 4; cc++) {
    int co = cog + 16*cc;
    size_t oi = ((size_t)(n*CO + co))*LTOK + t0 + tl;
    float a = c2[oi];
    #pragma unroll
    for (int h = 0; h < NH; h++) a = fmaf(pw[h][tl], rl[h][tl][co], a);
    out[oi] = a;
  }
}

extern "C" void kernel_launch(void* const* d_in, const int* in_sizes, int n_in,
                              void* d_out, int out_size, void* d_ws, size_t ws_size,
                              hipStream_t stream) {
  const float* x   = (const float*)d_in[0];
  const float* w1  = (const float*)d_in[1];
  const float* b1  = (const float*)d_in[2];
  const float* w2  = (const float*)d_in[3];
  const float* b2  = (const float*)d_in[4];
  const float* wm  = (const float*)d_in[5];
  const float* bm  = (const float*)d_in[6];
  const float* wa  = (const float*)d_in[7];
  const float* ba  = (const float*)d_in[8];
  const float* rot = (const float*)d_in[9];
  float* out = (float*)d_out;

  float* ws  = (float*)d_ws;
  float* up  = ws;                    // region A: upb (4.7MB), later xqb/xkb/qnb overlay
  float* c1  = up  + 2359296;         // region B: c1b (4.7MB) + c2b (4.7MB); later yvb over c1b
  float* c2  = c1  + 2359296;         // region C: c2 fp32 (9.4MB, combine residual)
  float* xep = c2  + 2359296;         // 1179648 fp32 [n][t][32] (conv_match out, hash source)
  float* bsc = xep + 1179648;         // 147456 fp32
  short* ret = (short*)(bsc + 147456);// 9437184 bf16
  int* codes  = (int*)(ret + 9437184);// 147456
  int* sidx   = codes + 147456;       // 147456
  int* hist   = sidx + 147456;        // 73728  [n][code][bb]
  int* bstart = hist + 73728;         // 73728  [n][code][bb]
  short* wpk = (short*)(bstart + 73728); // packed hi/lo weight planes (k_wprep3 layout)
  short* w1H = wpk;
  short* w1L = wpk + 36864;
  short* w2H = wpk + 73728;
  short* w2L = wpk + 110592;
  short* wmH = wpk + 147456;
  short* wmL = wpk + 165888;
  short* waH = wpk + 184320;
  short* waL = wpk + 188416;
  // bf16 activation buffers (pair-interleaved dwords)
  unsigned* upb = (unsigned*)up;          // [n][32][LTOK] dwords, dead after conv1
  unsigned* c1b = (unsigned*)c1;          // dead after conv2
  unsigned* c2b = (unsigned*)c1 + 1179648;// read by conv_match + conv1x1m
  // overlays (write-after-read ordering enforced by launch order)
  short* xqb = (short*)up;            // 1179648 shorts (after upb dead)
  short* xkb = xqb + 1179648;
  float* qnb = (float*)(xkb + 1179648);
  short* yvb = (short*)c1;            // 2359296 shorts (over dead c1b; c2b untouched)
  (void)in_sizes; (void)n_in; (void)out_size; (void)ws_size;

  k_wprep3<<<dim3((96256 + 255)/256), dim3(256), 0, stream>>>(w1, w2, wm, wa, wpk);
  k_upsample<<<dim3((NB*32*HH*WW + 255)/256), dim3(256), 0, stream>>>(x, upb);
  k_conv3m<false,true,false,true><<<dim3(NB*144*2), dim3(256), 0, stream>>>(upb, w1H, w1L, b1, nullptr, c1b, 64, 2);
  k_conv3m<false,true,true,true><<<dim3(NB*144*2), dim3(256), 0, stream>>>(c1b, w2H, w2L, b2, c2, c2b, 64, 2);
  k_conv3m<true,false,true,false><<<dim3(NB*144), dim3(256), 0, stream>>>(c2b, wmH, wmL, bm, xep, nullptr, 32, 1);
  k_conv1x1m<<<dim3(NB*144), dim3(256), 0, stream>>>(c2b, waH, waL, ba, yvb);
  k_hash<<<dim3(NB*NSB), dim3(SB), 0, stream>>>(xep, rot, codes, hist, xqb, xkb, qnb);
  k_offsets<<<dim3(NB), dim3(256), 0, stream>>>(hist, bstart);
  k_scatter<<<dim3(NB*NSB), dim3(SB), 0, stream>>>(codes, bstart, sidx);
  k_attn<<<dim3(NB*NH*NCHUNK/2), dim3(192), 0, stream>>>(xqb, xkb, qnb, yvb, sidx, ret, bsc);
  k_combine<<<dim3(NB*(LTOK/16)), dim3(256), 0, stream>>>(ret, bsc, c2, out);
}

// Round 15
// 297.041 us; speedup vs baseline: 1.2924x; 1.0084x over previous
//
#include <hip/hip_runtime.h>
#include <math.h>

#define NB 4
#define CIN 64
#define CO 64
#define CM 32
#define H0 48
#define W0 48
#define HH 96
#define WW 96
#define LTOK (HH*WW)     // 9216 tokens per image
#define NH 4
#define NBUCK 64
#define CHUNK 144
#define NCHUNK 64        // LTOK / CHUNK
#define TOT (NH*LTOK)    // 36864
#define SB 512
#define NSB (TOT/SB)     // 72

typedef __attribute__((ext_vector_type(8))) short short8;
typedef __attribute__((ext_vector_type(4))) short short4v;
typedef __attribute__((ext_vector_type(4))) float f32x4;

__device__ __forceinline__ short f2bf(float f) {          // RNE
  union { float f; unsigned u; } v; v.f = f;
  unsigned r = v.u + 0x7fffu + ((v.u >> 16) & 1u);
  return (short)(r >> 16);
}
__device__ __forceinline__ unsigned packbf(float a, float b) {
  return (unsigned)(unsigned short)f2bf(a) | (((unsigned)(unsigned short)f2bf(b)) << 16);
}
__device__ __forceinline__ short f2bf_fast(float f) {     // round-half-up (1 add)
  union { float f; unsigned u; } v; v.f = f;
  return (short)((v.u + 0x8000u) >> 16);
}
__device__ __forceinline__ float bf2f(short h) {
  union { float f; unsigned u; } v; v.u = ((unsigned)(unsigned short)h) << 16;
  return v.f;
}
__device__ __forceinline__ short8 ld_b64x2(const short* p) {  // 8B-aligned pair load
  short4v a = *(const short4v*)p;
  short4v b = *(const short4v*)(p+4);
  short8 r; r[0]=a[0];r[1]=a[1];r[2]=a[2];r[3]=a[3];r[4]=b[0];r[5]=b[1];r[6]=b[2];r[7]=b[3];
  return r;
}

// ---------------- bicubic upsample -> bf16 channel-pair-interleaved [n][ci/2][tok]x2 --------
__device__ __forceinline__ void cubic_taps(int o, int insz, int* p, float* w) {
  int j = o >> 1;
  const float B0=-0.0234375f, B1=0.2265625f, B2=0.8671875f, B3=-0.0703125f;
  if ((o & 1) == 0) { p[0]=j-2;p[1]=j-1;p[2]=j;  p[3]=j+1; w[0]=B0;w[1]=B1;w[2]=B2;w[3]=B3; }
  else              { p[0]=j-1;p[1]=j;  p[2]=j+1;p[3]=j+2; w[0]=B3;w[1]=B2;w[2]=B1;w[3]=B0; }
  float s = 0.f;
  #pragma unroll
  for (int a=0;a<4;a++){ if (p[a] < 0 || p[a] >= insz) p[a] = -1; else s += w[a]; }
  float inv = 1.f / s;
  #pragma unroll
  for (int a=0;a<4;a++) w[a] *= inv;
}

__global__ void k_upsample(const float* __restrict__ x, unsigned* __restrict__ upb) {
  int i = blockIdx.x*blockDim.x + threadIdx.x;   // NB*32*HH*WW: 2 channels per thread
  if (i >= NB*32*HH*WW) return;
  int ox = i % WW; int t = i / WW;
  int oy = t % HH; t /= HH;
  int c2 = t % 32; int n = t / 32;
  int px[4]; float wx[4]; cubic_taps(ox, W0, px, wx);
  int py[4]; float wy[4]; cubic_taps(oy, H0, py, wy);
  float a01[2];
  #pragma unroll
  for (int cc = 0; cc < 2; cc++) {
    const float* src = x + ((size_t)(n*CIN + 2*c2 + cc))*H0*W0;
    float acc = 0.f;
    #pragma unroll
    for (int a=0;a<4;a++) {
      if (py[a] < 0) continue;
      const float* r = src + py[a]*W0;
      float ra = 0.f;
      #pragma unroll
      for (int b=0;b<4;b++) if (px[b] >= 0) ra = fmaf(wx[b], r[px[b]], ra);
      acc = fmaf(wy[a], ra, acc);
    }
    a01[cc] = acc;
  }
  upb[((size_t)(n*32 + c2))*LTOK + oy*WW + ox] = packbf(a01[0], a01[1]);
}

// ---------------- weight prep (all four convs in ONE launch) --------------------------------
// layout: w1H w1L w2H w2L (36864 each) wmH wmL (18432 each) waH waL (4096 each)
__global__ void k_wprep3(const float* __restrict__ w1, const float* __restrict__ w2,
                         const float* __restrict__ wm, const float* __restrict__ wa,
                         short* __restrict__ base) {
  int i = blockIdx.x*blockDim.x + threadIdx.x;
  if (i >= 96256) return;
  if (i >= 92160) {                              // conv_assembly 1x1: [co][ci]
    int j = i - 92160;
    float v = wa[j];
    short hi = f2bf(v);
    base[184320 + j] = hi;
    base[188416 + j] = f2bf(v - bf2f(hi));
    return;
  }
  const float* src; short *dH, *dL; int couts, j;
  if (i < 36864)      { src = w1; couts = 64; j = i;          dH = base;          dL = base + 36864; }
  else if (i < 73728) { src = w2; couts = 64; j = i - 36864;  dH = base + 73728;  dL = base + 110592; }
  else                { src = wm; couts = 32; j = i - 73728;  dH = base + 147456; dL = base + 165888; }
  int ci = j & 63; int t = j >> 6; int co = t % couts; int s = t / couts;
  float v = src[((size_t)(co*64 + ci))*9 + s];
  short hi = f2bf(v);
  dH[j] = hi;
  dL[j] = f2bf(v - bf2f(hi));
}

// ---------------- 3x3 conv as implicit GEMM, 64-token tiles, bf16-pair input ----------------
#define XP 68   // X LDS pitch in shorts (136B: 8B-aligned b64 frags)
#define WP 72   // W LDS pitch in shorts (144B: 16B-aligned b128 frags)
template<bool TMAJ, bool RELU, bool WF, bool WB>
__global__ __launch_bounds__(256) void k_conv3m(const unsigned* __restrict__ in,
                          const short* __restrict__ wH, const short* __restrict__ wL,
                          const float* __restrict__ bias, float* __restrict__ outF,
                          unsigned* __restrict__ outB, int couts_tot, int cosplit) {
  int blk = blockIdx.x;              // NB * 144 * cosplit
  int ch = blk % cosplit;
  int tb = (blk / cosplit) % 144;
  int n  = blk / (cosplit * 144);
  int t0 = tb * 64;
  int co0 = ch * 32;
  int tid = threadIdx.x;
  int wv = tid >> 6, lane = tid & 63, quad = lane >> 4, l16 = lane & 15;
  __shared__ __align__(16) short XB[64*XP];
  __shared__ __align__(16) short WHs[32*WP];
  __shared__ __align__(16) short WLs[32*WP];
  __shared__ float biasl[32];
  if (tid < 32) biasl[tid] = bias[co0 + tid];
  f32x4 acc[2];
  acc[0] = (f32x4){0.f,0.f,0.f,0.f}; acc[1] = (f32x4){0.f,0.f,0.f,0.f};

  const unsigned* inb = in + (size_t)n*32*LTOK;
  for (int s = 0; s < 9; s++) {
    int dy = s/3 - 1, dx = s%3 - 1;
    __syncthreads();
    // ---- stage X: 64 tok x 32 ci-pair dwords (2048 tasks, 8/thread) ----
    #pragma unroll
    for (int it = 0; it < 8; it++) {
      int idx = tid + 256*it;
      int tok = idx & 63, c = idx >> 6;
      int t = t0 + tok;
      int y = t / WW, x = t - y*WW;
      int ys = y + dy, xs = x + dx;
      unsigned pk = 0;
      if ((unsigned)ys < HH && (unsigned)xs < WW)
        pk = inb[(size_t)c*LTOK + ys*WW + xs];
      ((unsigned*)XB)[tok*(XP/2) + c] = pk;
    }
    // ---- stage W hi+lo: 32 co x 64 ci (2048 dwords) ----
    #pragma unroll
    for (int it = 0; it < 8; it++) {
      int idx = tid + 256*it;
      int plane = idx >> 10, rem = idx & 1023;
      int co = rem >> 5, d = rem & 31;
      const unsigned* srcw = (const unsigned*)(plane ? wL : wH);
      unsigned v = srcw[(size_t)(s*couts_tot + co0 + co)*32 + d];
      unsigned* dst = (unsigned*)(plane ? WLs : WHs);
      dst[co*(WP/2) + d] = v;
    }
    __syncthreads();
    #pragma unroll
    for (int kf = 0; kf < 2; kf++) {
      short8 xf = ld_b64x2(&XB[(wv*16 + l16)*XP + kf*32 + quad*8]);
      if (!TMAJ) {
        // D[m=co][n=tok]: A = W (hi then lo), B = X
        #pragma unroll
        for (int mt=0;mt<2;mt++) {
          short8 wh = *(const short8*)&WHs[(mt*16 + l16)*WP + kf*32 + quad*8];
          short8 wl = *(const short8*)&WLs[(mt*16 + l16)*WP + kf*32 + quad*8];
          acc[mt] = __builtin_amdgcn_mfma_f32_16x16x32_bf16(wh, xf, acc[mt], 0, 0, 0);
          acc[mt] = __builtin_amdgcn_mfma_f32_16x16x32_bf16(wl, xf, acc[mt], 0, 0, 0);
        }
      } else {
        // D[m=tok][n=co]: A = X, B = W
        #pragma unroll
        for (int nt=0;nt<2;nt++) {
          short8 wh = *(const short8*)&WHs[(nt*16 + l16)*WP + kf*32 + quad*8];
          short8 wl = *(const short8*)&WLs[(nt*16 + l16)*WP + kf*32 + quad*8];
          acc[nt] = __builtin_amdgcn_mfma_f32_16x16x32_bf16(xf, wh, acc[nt], 0, 0, 0);
          acc[nt] = __builtin_amdgcn_mfma_f32_16x16x32_bf16(xf, wl, acc[nt], 0, 0, 0);
        }
      }
    }
  }
  if (!TMAJ) {
    int tokl = wv*16 + l16;
    #pragma unroll
    for (int mt=0;mt<2;mt++) {
      float v[4];
      #pragma unroll
      for (int reg=0;reg<4;reg++) {
        int col = mt*16 + quad*4 + reg;
        v[reg] = acc[mt][reg] + biasl[col];
        if (RELU) v[reg] = fmaxf(v[reg], 0.f);
      }
      int colb = mt*16 + quad*4;
      if (WF) {
        #pragma unroll
        for (int reg=0;reg<4;reg++)
          outF[((size_t)(n*couts_tot + co0 + colb + reg))*LTOK + t0 + tokl] = v[reg];
      }
      if (WB) {
        size_t nb = (size_t)n*(couts_tot >> 1);
        outB[(nb + ((co0 + colb) >> 1))*LTOK + t0 + tokl]     = packbf(v[0], v[1]);
        outB[(nb + ((co0 + colb + 2) >> 1))*LTOK + t0 + tokl] = packbf(v[2], v[3]);
      }
    }
  } else {       // fp32 token-major (conv_match -> xep)
    #pragma unroll
    for (int nt=0;nt<2;nt++) {
      int co = nt*16 + l16;
      #pragma unroll
      for (int reg=0;reg<4;reg++) {
        int t = t0 + wv*16 + quad*4 + reg;
        float v = acc[nt][reg] + biasl[co];
        if (RELU) v = fmaxf(v, 0.f);
        outF[((size_t)n*LTOK + t)*couts_tot + co] = v;
      }
    }
  }
}

// ---------------- 1x1 conv as bf16 MFMA GEMM (bf16-pair input) -> bf16 V [n][t][64] ---------
__global__ __launch_bounds__(256) void k_conv1x1m(const unsigned* __restrict__ in,
                          const short* __restrict__ wH, const short* __restrict__ wL,
                          const float* __restrict__ bias, short* __restrict__ out) {
  int blk = blockIdx.x;           // NB * 144
  int n  = blk / 144;
  int t0 = (blk % 144) * 64;
  int tid = threadIdx.x;
  int wv = tid >> 6, lane = tid & 63, quad = lane >> 4, l16 = lane & 15;
  __shared__ __align__(16) short XB[64*XP];
  __shared__ __align__(16) short WHs[64*WP];
  __shared__ __align__(16) short WLs[64*WP];
  __shared__ float biasl[64];
  if (tid < 64) biasl[tid] = bias[tid];
  const unsigned* inb = in + (size_t)n*32*LTOK;
  #pragma unroll
  for (int it = 0; it < 8; it++) {          // X: 64 tok x 32 ci-pair dwords
    int idx = tid + 256*it;
    int tok = idx & 63, c = idx >> 6;
    ((unsigned*)XB)[tok*(XP/2) + c] = inb[(size_t)c*LTOK + t0 + tok];
  }
  #pragma unroll
  for (int it = 0; it < 16; it++) {         // W hi/lo: 64 co x 32 dwords x 2 planes
    int idx = tid + 256*it;
    int plane = idx >> 11, rem = idx & 2047;
    int co = rem >> 5, d = rem & 31;
    const unsigned* srcw = (const unsigned*)(plane ? wL : wH);
    unsigned v = srcw[(size_t)co*32 + d];
    unsigned* dst = (unsigned*)(plane ? WLs : WHs);
    dst[co*(WP/2) + d] = v;
  }
  __syncthreads();
  f32x4 acc[4];
  #pragma unroll
  for (int i=0;i<4;i++) acc[i] = (f32x4){0.f,0.f,0.f,0.f};
  #pragma unroll
  for (int kf = 0; kf < 2; kf++) {
    short8 xf = ld_b64x2(&XB[(wv*16 + l16)*XP + kf*32 + quad*8]);
    #pragma unroll
    for (int nt=0;nt<4;nt++) {
      short8 wh = *(const short8*)&WHs[(nt*16 + l16)*WP + kf*32 + quad*8];
      short8 wl = *(const short8*)&WLs[(nt*16 + l16)*WP + kf*32 + quad*8];
      acc[nt] = __builtin_amdgcn_mfma_f32_16x16x32_bf16(xf, wh, acc[nt], 0, 0, 0);
      acc[nt] = __builtin_amdgcn_mfma_f32_16x16x32_bf16(xf, wl, acc[nt], 0, 0, 0);
    }
  }
  #pragma unroll
  for (int nt=0;nt<4;nt++) {
    int co = nt*16 + l16;
    #pragma unroll
    for (int reg=0;reg<4;reg++) {
      int t = t0 + wv*16 + quad*4 + reg;
      out[((size_t)n*LTOK + t)*CO + co] = f2bf(acc[nt][reg] + biasl[co]);
    }
  }
}

// ---------------- LSH hash (+ fused token prep in h==0 blocks) ------------------------------
// hist layout: [n][code][bb] so k_offsets reads are per-thread contiguous.
__global__ void k_hash(const float* __restrict__ xe, const float* __restrict__ rot,
                       int* __restrict__ codes, int* __restrict__ hist,
                       short* __restrict__ xqb, short* __restrict__ xkb,
                       float* __restrict__ qnb) {
  int b  = blockIdx.x;
  int n  = b / NSB;
  int bb = b % NSB;
  int j  = bb*SB + threadIdx.x;
  int h  = j / LTOK;             // uniform per block (LTOK = 18*SB)
  int t  = j % LTOK;
  __shared__ float rl[CM][NBUCK/2];
  __shared__ int lh[256];
  for (int e = threadIdx.x; e < 256; e += SB) lh[e] = 0;
  for (int e = threadIdx.x; e < CM*(NBUCK/2); e += SB) {
    int f = e / 32, i = e % 32;
    rl[f][i] = rot[(f*NH + h)*32 + i];
  }
  __syncthreads();
  float q[CM];
  const float4* xr4 = (const float4*)(xe + ((size_t)n*LTOK + t)*CM);
  #pragma unroll
  for (int r = 0; r < 8; r++) {
    float4 v = xr4[r];
    q[4*r+0]=v.x; q[4*r+1]=v.y; q[4*r+2]=v.z; q[4*r+3]=v.w;
  }
  // fused prep: h==0 blocks emit bf16 Q rows, bf16 normalized K rows, norms (once per token)
  if (bb < LTOK/SB) {
    float ssq = 0.f;
    #pragma unroll
    for (int f = 0; f < CM; f++) ssq = fmaf(q[f], q[f], ssq);
    float nrm = sqrtf(ssq);
    float rn = 1.f / fmaxf(nrm, 5e-5f);
    qnb[(size_t)n*LTOK + t] = nrm;
    #pragma unroll
    for (int r = 0; r < 4; r++) {
      short8 q8, k8;
      #pragma unroll
      for (int jj = 0; jj < 8; jj++) { q8[jj] = f2bf(q[8*r+jj]); k8[jj] = f2bf(q[8*r+jj]*rn); }
      *(short8*)&xqb[((size_t)n*LTOK + t)*CM + 8*r] = q8;
      *(short8*)&xkb[((size_t)n*LTOK + t)*CM + 8*r] = k8;
    }
  }
  float bp = -INFINITY, bn = -INFINITY; int ip = 0, inn = 0;
  for (int i = 0; i < 32; i++) {
    float acc = 0.f;
    #pragma unroll
    for (int f = 0; f < CM; f++) acc = fmaf(q[f], rl[f][i], acc);
    if (acc  > bp) { bp = acc;  ip  = i; }
    if (-acc > bn) { bn = -acc; inn = i; }
  }
  int code = (bp >= bn) ? ip : (32 + inn);
  code += h * NBUCK;
  codes[n*TOT + j] = code;
  atomicAdd(&lh[code], 1);
  __syncthreads();
  for (int e = threadIdx.x; e < 256; e += SB) hist[((size_t)(n*256 + e))*NSB + bb] = lh[e];
}

// ---------------- stable counting sort (transposed hist: contiguous per-thread runs) --------
__global__ void k_offsets(const int* __restrict__ hist, int* __restrict__ bstart) {
  int n = blockIdx.x; int c = threadIdx.x;
  const int* hrow = hist + (size_t)(n*256 + c)*NSB;
  int tot = 0;
  for (int b = 0; b < NSB; b++) tot += hrow[b];
  __shared__ int sc[256];
  sc[c] = tot;
  __syncthreads();
  for (int d = 1; d < 256; d <<= 1) {
    int u = (c >= d) ? sc[c-d] : 0;
    __syncthreads();
    sc[c] += u;
    __syncthreads();
  }
  int run = sc[c] - tot;
  int* brow = bstart + (size_t)(n*256 + c)*NSB;
  for (int b = 0; b < NSB; b++) {
    brow[b] = run;
    run += hrow[b];
  }
}

// ballot-based stable rank: rank = #earlier-threads-in-block with same code.
__global__ void k_scatter(const int* __restrict__ codes, const int* __restrict__ bstart,
                          int* __restrict__ sidx) {
  int b = blockIdx.x; int n = b / NSB; int bb = b % NSB;
  int tid = threadIdx.x;
  int j = bb*SB + tid;
  int code = codes[n*TOT + j];
  int wave = tid >> 6, lane = tid & 63;
  __shared__ int wcnt[8][256];
  for (int e = tid; e < 8*256; e += SB) ((int*)wcnt)[e] = 0;
  __syncthreads();
  unsigned long long mask = ~0ULL;
  #pragma unroll
  for (int bit = 0; bit < 8; bit++) {
    unsigned long long bal = __ballot((code >> bit) & 1);
    mask &= ((code >> bit) & 1) ? bal : ~bal;
  }
  unsigned long long lt = (lane == 63) ? 0x7FFFFFFFFFFFFFFFULL : ((1ULL << lane) - 1ULL);
  int rank_w = __popcll(mask & lt);
  if (rank_w == 0) wcnt[wave][code] = __popcll(mask);
  __syncthreads();
  int rank = rank_w;
  for (int w2 = 0; w2 < 8; w2++) {
    if (w2 >= wave) break;
    rank += wcnt[w2][code];
  }
  int pos = bstart[((size_t)(n*256 + code))*NSB + bb] + rank;
  sidx[n*TOT + pos] = j;
}

// ---------------- MFMA bf16 flash attention: 64-key S->PV groups, 43KB LDS (3 blocks/CU) ----
// Pq holds only one 64-key group's P (wave-private rows; no barriers between S and PV —
// per-wave LDS ordering guarantees the write->read). Key accumulation order identical to the
// full-tile version -> bit-identical output. Last group (16 keys): P cols 16..31 are stale
// finite values x VbT's zeroed cols 144..159 = exact 0.
#define PQ2 72    // P pitch in shorts (64 cols + 8 pad; 16B aligned)
#define VT2 168   // V^T pitch in shorts (160 cols + 8 pad; 16B aligned)
__global__ __launch_bounds__(192,1) void k_attn(const short* __restrict__ xqb,
                       const short* __restrict__ xkb, const float* __restrict__ qnb,
                       const short* __restrict__ yvb, const int* __restrict__ sidx,
                       short* __restrict__ ret, float* __restrict__ bsc) {
  int raw = blockIdx.x;               // 512 = NB*NH*NCHUNK/2
  int xcd = raw & 7;
  int n = xcd >> 1;
  int idx2 = ((raw >> 3) << 1) | (xcd & 1);   // 0..127
  int h = idx2 >> 5;
  int cpair = idx2 & 31;
  const int base = n*TOT + h*LTOK;
  __shared__ __align__(16) short Pq[144*PQ2];   // 20.7 KB: one 64-key group's P
  __shared__ __align__(16) short VbT[64*VT2];   // 21.5 KB: V^T, cols 144..159 zero pad
  __shared__ int sj[3*CHUNK];
  int tid = threadIdx.x;
  int w = tid >> 6, lane = tid & 63, quad = lane >> 4, l16 = lane & 15;
  const short* xq = xqb + (size_t)n*LTOK*CM;
  const short* xk = xkb + (size_t)n*LTOK*CM;
  const short* yv = yvb + (size_t)n*LTOK*CO;
  const float* qn = qnb + (size_t)n*LTOK;

  // zero V^T pad cols 144..159 once (512 dwords). Pq needs no zeroing: PV reads cols <= 63,
  // and the g=2 stale cols are always prior-group finite values.
  for (int e = tid; e < 64*8; e += 192) {
    int r = e >> 3, d = e & 7;
    ((unsigned*)VbT)[r*(VT2/2) + 72 + d] = 0u;
  }

  for (int ch2 = 0; ch2 < 2; ch2++) {
    int kch = cpair*2 + ch2;
    int kprev = (kch + NCHUNK - 1) & (NCHUNK-1), knext = (kch + 1) & (NCHUNK-1);
    __syncthreads();
    for (int e = tid; e < 3*CHUNK; e += 192) {
      int tt = e / CHUNK, r = e - tt*CHUNK;
      int kk = (tt==0) ? kch : ((tt==1) ? kprev : knext);
      sj[e] = sidx[base + kk*CHUNK + r];
    }
    __syncthreads();
    short8 qfrag[3]; float m_ln[3][4];
    #pragma unroll
    for (int mt=0;mt<3;mt++) {
      int tok = sj[48*w + 16*mt + l16] % LTOK;
      qfrag[mt] = *(const short8*)(xq + (size_t)tok*CM + quad*8);
      #pragma unroll
      for (int r=0;r<4;r++)
        m_ln[mt][r] = qn[sj[48*w + 16*mt + 4*quad + r] % LTOK];
    }
    f32x4 acc[3][4];
    #pragma unroll
    for (int mt=0;mt<3;mt++)
      #pragma unroll
      for (int nt=0;nt<4;nt++) acc[mt][nt] = (f32x4){0.f,0.f,0.f,0.f};
    float sspart[12];
    #pragma unroll
    for (int i=0;i<12;i++) sspart[i]=0.f;

    for (int tt = 0; tt < 3; tt++) {
      __syncthreads();   // previous tile's VbT fully consumed
      // ---- stage V^T (bf16 copy-transpose): 8 ch-groups x 144 keys ----
      #pragma unroll
      for (int it = 0; it < 6; it++) {
        int idx = tid + 192*it;
        int g = idx / CHUNK, key = idx - g*CHUNK;
        int tok = sj[tt*CHUNK + key] % LTOK;
        short8 v = *(const short8*)(yv + (size_t)tok*CO + 8*g);
        #pragma unroll
        for (int i=0;i<8;i++) VbT[(8*g+i)*VT2 + key] = v[i];
      }
      __syncthreads();
      int ktok[9];
      #pragma unroll
      for (int nt=0;nt<9;nt++) ktok[nt] = sj[tt*CHUNK + 16*nt + l16] % LTOK;
      // ---- 3 groups of 64 keys: batched S (4 n-tiles) -> batched PV (2 k-frags) ----
      #pragma unroll
      for (int g = 0; g < 3; g++) {
        int nts = (g < 2) ? 4 : 1;
        #pragma unroll
        for (int lnt = 0; lnt < 4; lnt++) {
          if (lnt >= nts) break;
          int nt = 4*g + lnt;
          short8 bfr = *(const short8*)(xk + (size_t)ktok[nt]*CM + quad*8);
          f32x4 c[3];
          #pragma unroll
          for (int mt=0;mt<3;mt++)
            c[mt] = __builtin_amdgcn_mfma_f32_16x16x32_bf16(qfrag[mt], bfr, (f32x4){0.f,0.f,0.f,0.f}, 0, 0, 0);
          #pragma unroll
          for (int mt=0;mt<3;mt++) {
            #pragma unroll
            for (int reg=0;reg<4;reg++) {
              float p = __expf(c[mt][reg] - m_ln[mt][reg]);
              sspart[mt*4+reg] += p;
              Pq[(48*w + 16*mt + 4*quad + reg)*PQ2 + 16*lnt + l16] = f2bf_fast(p);
            }
          }
        }
        int kfs = (g < 2) ? 2 : 1;
        #pragma unroll
        for (int kf = 0; kf < 2; kf++) {
          if (kf >= kfs) break;
          short8 afr[3];
          #pragma unroll
          for (int mt=0;mt<3;mt++)
            afr[mt] = *(const short8*)&Pq[(48*w + 16*mt + l16)*PQ2 + kf*32 + quad*8];
          #pragma unroll
          for (int nt2=0;nt2<4;nt2++) {
            short8 vfr = *(const short8*)&VbT[(16*nt2 + l16)*VT2 + 64*g + kf*32 + quad*8];
            #pragma unroll
            for (int mt=0;mt<3;mt++)
              acc[mt][nt2] = __builtin_amdgcn_mfma_f32_16x16x32_bf16(afr[mt], vfr, acc[mt][nt2], 0, 0, 0);
          }
        }
      }
    }
    #pragma unroll
    for (int i=0;i<12;i++) {
      float v = sspart[i];
      v += __shfl_xor(v, 1); v += __shfl_xor(v, 2);
      v += __shfl_xor(v, 4); v += __shfl_xor(v, 8);
      sspart[i] = v;
    }
    #pragma unroll
    for (int mt=0;mt<3;mt++) {
      #pragma unroll
      for (int reg=0;reg<4;reg++) {
        int row = 48*w + 16*mt + 4*quad + reg;
        int mtok = sj[row];
        float ssum = sspart[mt*4+reg];
        float inv = 1.f / ssum;
        short* rp = ret + ((size_t)n*TOT + mtok)*CO;
        #pragma unroll
        for (int nt2=0;nt2<4;nt2++) rp[16*nt2 + l16] = f2bf(acc[mt][nt2][reg] * inv);
        if (l16 == 0) bsc[(size_t)n*TOT + mtok] = m_ln[mt][reg] + logf(ssum);
      }
    }
  }
}

// ---------------- combine 4 hash rounds (softmax over bscore) + residual, NCHW out ----------
__global__ void k_combine(const short* __restrict__ ret, const float* __restrict__ bsc,
                          const float* __restrict__ c2, float* __restrict__ out) {
  int blk = blockIdx.x;                 // NB * (LTOK/16)
  int n  = blk / (LTOK/16);
  int t0 = (blk % (LTOK/16)) * 16;
  __shared__ float rl[NH][16][CO+1];
  __shared__ float pw[NH][16];
  int tid = threadIdx.x;
  for (int h = 0; h < NH; h++)
    for (int e = tid; e < 16*CO; e += 256) {
      int tl = e >> 6, f = e & 63;
      rl[h][tl][f] = bf2f(ret[((size_t)n*TOT + h*LTOK + t0 + tl)*CO + f]);
    }
  if (tid < 16) {
    float b0[NH]; float mm = -INFINITY;
    #pragma unroll
    for (int h = 0; h < NH; h++) { b0[h] = bsc[(size_t)n*TOT + h*LTOK + t0 + tid]; mm = fmaxf(mm, b0[h]); }
    float s = 0.f;
    #pragma unroll
    for (int h = 0; h < NH; h++) { b0[h] = __expf(b0[h] - mm); s += b0[h]; }
    float inv = 1.f / s;
    #pragma unroll
    for (int h = 0; h < NH; h++) pw[h][tid] = b0[h] * inv;
  }
  __syncthreads();
  int tl = tid & 15;
  int cog = tid >> 4;
  #pragma unroll
  for (int cc = 0; cc < 4; cc++) {
    int co = cog + 16*cc;
    size_t oi = ((size_t)(n*CO + co))*LTOK + t0 + tl;
    float a = c2[oi];
    #pragma unroll
    for (int h = 0; h < NH; h++) a = fmaf(pw[h][tl], rl[h][tl][co], a);
    out[oi] = a;
  }
}

extern "C" void kernel_launch(void* const* d_in, const int* in_sizes, int n_in,
                              void* d_out, int out_size, void* d_ws, size_t ws_size,
                              hipStream_t stream) {
  const float* x   = (const float*)d_in[0];
  const float* w1  = (const float*)d_in[1];
  const float* b1  = (const float*)d_in[2];
  const float* w2  = (const float*)d_in[3];
  const float* b2  = (const float*)d_in[4];
  const float* wm  = (const float*)d_in[5];
  const float* bm  = (const float*)d_in[6];
  const float* wa  = (const float*)d_in[7];
  const float* ba  = (const float*)d_in[8];
  const float* rot = (const float*)d_in[9];
  float* out = (float*)d_out;

  float* ws  = (float*)d_ws;
  float* up  = ws;                    // region A: upb (4.7MB), later xqb/xkb/qnb overlay
  float* c1  = up  + 2359296;         // region B: c1b (4.7MB) + c2b (4.7MB); later yvb over c1b
  float* c2  = c1  + 2359296;         // region C: c2 fp32 (9.4MB, combine residual)
  float* xep = c2  + 2359296;         // 1179648 fp32 [n][t][32] (conv_match out, hash source)
  float* bsc = xep + 1179648;         // 147456 fp32
  short* ret = (short*)(bsc + 147456);// 9437184 bf16
  int* codes  = (int*)(ret + 9437184);// 147456
  int* sidx   = codes + 147456;       // 147456
  int* hist   = sidx + 147456;        // 73728  [n][code][bb]
  int* bstart = hist + 73728;         // 73728  [n][code][bb]
  short* wpk = (short*)(bstart + 73728); // packed hi/lo weight planes (k_wprep3 layout)
  short* w1H = wpk;
  short* w1L = wpk + 36864;
  short* w2H = wpk + 73728;
  short* w2L = wpk + 110592;
  short* wmH = wpk + 147456;
  short* wmL = wpk + 165888;
  short* waH = wpk + 184320;
  short* waL = wpk + 188416;
  // bf16 activation buffers (pair-interleaved dwords)
  unsigned* upb = (unsigned*)up;          // [n][32][LTOK] dwords, dead after conv1
  unsigned* c1b = (unsigned*)c1;          // dead after conv2
  unsigned* c2b = (unsigned*)c1 + 1179648;// read by conv_match + conv1x1m
  // overlays (write-after-read ordering enforced by launch order)
  short* xqb = (short*)up;            // 1179648 shorts (after upb dead)
  short* xkb = xqb + 1179648;
  float* qnb = (float*)(xkb + 1179648);
  short* yvb = (short*)c1;            // 2359296 shorts (over dead c1b; c2b untouched)
  (void)in_sizes; (void)n_in; (void)out_size; (void)ws_size;

  k_wprep3<<<dim3((96256 + 255)/256), dim3(256), 0, stream>>>(w1, w2, wm, wa, wpk);
  k_upsample<<<dim3((NB*32*HH*WW + 255)/256), dim3(256), 0, stream>>>(x, upb);
  k_conv3m<false,true,false,true><<<dim3(NB*144*2), dim3(256), 0, stream>>>(upb, w1H, w1L, b1, nullptr, c1b, 64, 2);
  k_conv3m<false,true,true,true><<<dim3(NB*144*2), dim3(256), 0, stream>>>(c1b, w2H, w2L, b2, c2, c2b, 64, 2);
  k_conv3m<true,false,true,false><<<dim3(NB*144), dim3(256), 0, stream>>>(c2b, wmH, wmL, bm, xep, nullptr, 32, 1);
  k_conv1x1m<<<dim3(NB*144), dim3(256), 0, stream>>>(c2b, waH, waL, ba, yvb);
  k_hash<<<dim3(NB*NSB), dim3(SB), 0, stream>>>(xep, rot, codes, hist, xqb, xkb, qnb);
  k_offsets<<<dim3(NB), dim3(256), 0, stream>>>(hist, bstart);
  k_scatter<<<dim3(NB*NSB), dim3(SB), 0, stream>>>(codes, bstart, sidx);
  k_attn<<<dim3(NB*NH*NCHUNK/2), dim3(192), 0, stream>>>(xqb, xkb, qnb, yvb, sidx, ret, bsc);
  k_combine<<<dim3(NB*(LTOK/16)), dim3(256), 0, stream>>>(ret, bsc, c2, out);
}